// Round 8
// baseline (499.466 us; speedup 1.0000x reference)
//
#include <hip/hip_runtime.h>

// LocalFeatureAggregation — round 11: r10 pipeline, spill-free retest.
//  * r10 post-mortem: 3rd spill strike. Under (64,2) w/ 64-thr blocks the
//    allocator HARD-TARGETS 128 arch VGPRs (r8=116 fit, r9=128 wall, r10's
//    +30 live regs -> 72MB scratch stores). The pipeline was never tested
//    unspilled.
//  * Fix: __launch_bounds__(64,1) lifts the reg ceiling (~512); ~160 live regs
//    allocate cleanly. Theoretical cap 2 waves/SIMD = 8/CU == measured ~7/CU
//    residency of EVERY config so far -> nothing real is lost.
//  * Diet for margin: WNBf preload dropped (per-tile L1 loads, as r9);
//    gather prefetch lands directly in gv (dead after early gather-writes).
//  * Gate: WRITE_SIZE must be ~65.5MB / FETCH ~146MB. If spilled again ->
//    abandon pipeline. If clean but ~247us -> prefetch adds nothing; next
//    lever is phase-2 (WB->MFMA chains). If clean and <225 -> pipeline real.
// Requires ws_size >= 16864256 for the fast path (>= 86784 for fallback).

#define KNB   16
#define CR    10
#define CIN   64
#define CCAT  128
#define COUT  128
#define NPTS  131072
#define EPS   1e-5f
#define LOG2E 1.4426950408889634f

// d_ws layout (bytes)
#define WS_WB   0        // W_attn B-frags (pre-scaled by log2e): 2048 * 16 B = 32768
#define WS_W3   32768    // [W_out;W_sc] BN-folded B-frags: 3072 * 16 B = 49152
#define WS_WNB  81920    // W_nb BN-folded B-frags (K padded to 32): 256 * 16 B = 4096
#define WS_B3   86016    // bias3[128] fp32
#define WS_BNB  86528    // binb[64] fp32   -> 86784
#define WS_FEA  87040    // bf16 feature table [NPTS][CIN]: 16777216 B -> total 16864256

typedef const float* fp;
typedef short bf16x8 __attribute__((ext_vector_type(8)));
typedef float f32x4  __attribute__((ext_vector_type(4)));
typedef __bf16 bf16x2 __attribute__((ext_vector_type(2)));

__device__ __forceinline__ unsigned short f2bf(float x) {
    return __builtin_bit_cast(unsigned short, (__bf16)x);     // HW RNE cvt
}
__device__ __forceinline__ unsigned int pack2(float a, float b) {
    bf16x2 v; v.x = (__bf16)a; v.y = (__bf16)b;               // v_cvt_pk_bf16_f32
    return __builtin_bit_cast(unsigned int, v);
}
__device__ __forceinline__ float bf2f(unsigned short h) {
    return __uint_as_float(((unsigned int)h) << 16);
}
__device__ __forceinline__ float lrelu(float x) { return fmaxf(x, 0.2f * x); }

// ---------------------------------------------------------------------------
// Prep: build all weight-fragment tables in d_ws.
// ---------------------------------------------------------------------------
__global__ __launch_bounds__(256) void lfa_prep(
    fp W_nb, fp b_nb, fp g_nb, fp be_nb, fp m_nb, fp v_nb,
    fp W_attn,
    fp W_out, fp b_out, fp g_out, fp be_out, fp m_out, fp v_out,
    fp W_sc,  fp b_sc,  fp g_sc,  fp be_sc,  fp m_sc,  fp v_sc,
    unsigned char* __restrict__ ws)
{
    const int t = blockIdx.x * 256 + threadIdx.x;
    if (t < 2048) {                                   // W_attn frags (x log2e)
        const int n0 = t >> 8, s = (t >> 6) & 3, ln = t & 63;
        const int n = (n0 << 4) + (ln & 15);
        unsigned int v[4];
        #pragma unroll
        for (int jj = 0; jj < 4; ++jj) {
            const int k = (s << 5) + ((ln >> 4) << 3) + jj * 2;
            v[jj] = pack2(W_attn[k * CCAT + n] * LOG2E,
                          W_attn[(k + 1) * CCAT + n] * LOG2E);
        }
        *(uint4*)(ws + WS_WB + t * 16) = make_uint4(v[0], v[1], v[2], v[3]);
    } else if (t < 5120) {                            // [W_out;W_sc] BN-folded frags
        const int e = t - 2048;
        const int t8 = e / 384, rem = e % 384, s = rem >> 6, ln = rem & 63;
        const int d = (t8 << 4) + (ln & 15);
        const float so = g_out[d] * rsqrtf(v_out[d] + EPS);
        const float ss = g_sc[d]  * rsqrtf(v_sc[d]  + EPS);
        unsigned int v[4];
        #pragma unroll
        for (int jj = 0; jj < 4; ++jj) {
            float a[2];
            #pragma unroll
            for (int h = 0; h < 2; ++h) {
                const int k = (s << 5) + ((ln >> 4) << 3) + jj * 2 + h;   // 0..191
                a[h] = (k < CCAT) ? W_out[k * COUT + d] * so
                                  : W_sc[(k - CCAT) * COUT + d] * ss;
            }
            v[jj] = pack2(a[0], a[1]);
        }
        *(uint4*)(ws + WS_W3 + e * 16) = make_uint4(v[0], v[1], v[2], v[3]);
    } else if (t < 5376) {                            // W_nb BN-prescaled frags
        const int e = t - 5120;
        const int n0 = e >> 6, ln = e & 63;
        const int n = (n0 << 4) + (ln & 15);
        const float sn = g_nb[n] * rsqrtf(v_nb[n] + EPS);
        unsigned int v[4];
        #pragma unroll
        for (int jj = 0; jj < 4; ++jj) {
            float a[2];
            #pragma unroll
            for (int h = 0; h < 2; ++h) {
                const int k = ((ln >> 4) << 3) + jj * 2 + h;
                a[h] = (k < CR) ? W_nb[k * 64 + n] * sn : 0.f;
            }
            v[jj] = pack2(a[0], a[1]);
        }
        *(uint4*)(ws + WS_WNB + e * 16) = make_uint4(v[0], v[1], v[2], v[3]);
    } else if (t < 5504) {                            // bias3
        const int d = t - 5376;
        const float so = g_out[d] * rsqrtf(v_out[d] + EPS);
        const float ss = g_sc[d]  * rsqrtf(v_sc[d]  + EPS);
        ((float*)(ws + WS_B3))[d] =
              (b_out[d] - m_out[d]) * so + be_out[d]
            + (b_sc[d]  - m_sc[d])  * ss + be_sc[d];
    } else if (t < 5568) {                            // nb bias
        const int d = t - 5504;
        const float sn = g_nb[d] * rsqrtf(v_nb[d] + EPS);
        ((float*)(ws + WS_BNB))[d] = (b_nb[d] - m_nb[d]) * sn + be_nb[d];
    }
}

// ---------------------------------------------------------------------------
// Prep 2: bf16 feature table [NPTS][CIN] into ws+WS_FEA (8 ch per thread).
// ---------------------------------------------------------------------------
__global__ __launch_bounds__(256) void lfa_prep_fea(
    fp feature, unsigned char* __restrict__ ws)
{
    const int t = blockIdx.x * 256 + threadIdx.x;
    const size_t idx = (size_t)t * 8;
    if (idx < (size_t)NPTS * CIN) {
        const float4 f0 = *(const float4*)&feature[idx];
        const float4 f1 = *(const float4*)&feature[idx + 4];
        uint4 o;
        o.x = pack2(f0.x, f0.y); o.y = pack2(f0.z, f0.w);
        o.z = pack2(f1.x, f1.y); o.w = pack2(f1.z, f1.w);
        *(uint4*)(ws + WS_FEA + idx * 2) = o;
    }
}

// ---------------------------------------------------------------------------
// Main (fast path): 1-wave blocks, point-paired inner loop, cross-iteration
// software pipeline, (64,1) bounds so ~160 live regs allocate without spill.
// 8192 blocks x 64 thr, 16 pts/block. LDS = 15104 B.
// ---------------------------------------------------------------------------
__global__ __launch_bounds__(64, 1) void lfa_main_bf16(
    fp raw, const int* __restrict__ nidx,
    const unsigned char* __restrict__ ws, float* __restrict__ out)
{
    __shared__ __align__(16) unsigned short feaA[2][16][136];   // 8704 B
    __shared__ __align__(16) unsigned short pooledA[16][200];   // 6400 B

    const int lane = threadIdx.x;              // 0..63
    const int quad = lane >> 4;
    const int l15  = lane & 15;
    const int p0   = blockIdx.x * 16;          // block's 16 points
    const int b    = p0 >> 16;                 // batch (16-pt range never straddles)

    const unsigned short* feaT = (const unsigned short*)(ws + WS_FEA);
    const unsigned char*  wbp  = ws + WS_WB + ((size_t)lane << 4);

    // ---- hoisted: center rows for ALL 16 points -> pooledA[:,128..191] ----
    #pragma unroll
    for (int j = 0; j < 4; ++j) {
        const int e   = j * 64 + lane;         // 0..255
        const int row = e >> 4, c4 = (e & 15) * 4;
        const uint2 cf = *(const uint2*)&feaT[(size_t)(p0 + row) * CIN + c4];
        *(uint2*)&pooledA[row][CCAT + c4] = cf;
    }

    float binb[4];
    #pragma unroll
    for (int j = 0; j < 4; ++j)
        binb[j] = ((const float*)(ws + WS_BNB))[j * 16 + l15];

    // ---- prologue: stage it=0 (idx -> raw regs -> gathers) ----
    int idxv = 0;
    if (lane < 32) idxv = nidx[p0 * KNB + lane];

    float2 rw[2][4];                           // raw staging (quad-divergent use)
    #pragma unroll
    for (int pt = 0; pt < 2; ++pt) {
        const float* rp = raw + (size_t)(p0 + pt) * (KNB * CR) + l15 * CR;
        if (quad == 0) {
            rw[pt][0] = *(const float2*)(rp + 0);
            rw[pt][1] = *(const float2*)(rp + 2);
            rw[pt][2] = *(const float2*)(rp + 4);
            rw[pt][3] = *(const float2*)(rp + 6);
        } else if (quad == 1) {
            rw[pt][0] = *(const float2*)(rp + 8);
        }
    }

    uint2 gv[2][4];
    #pragma unroll
    for (int pt = 0; pt < 2; ++pt)
        #pragma unroll
        for (int i = 0; i < 4; ++i) {
            const int ni = __shfl(idxv, pt * 16 + i * 4 + quad, 64);
            gv[pt][i] = *(const uint2*)&feaT[(size_t)((b << 16) + ni) * CIN + l15 * 4];
        }

    #pragma unroll 1
    for (int it = 0; it < 8; ++it) {
        const int  pp0  = p0 + it * 2;
        const bool more = (it < 7);

        // ---- pack anb from raw regs staged LAST iteration (oldest in FIFO) ----
        bf16x8 anb[2];
        #pragma unroll
        for (int pt = 0; pt < 2; ++pt) {
            bf16x8 a = {0, 0, 0, 0, 0, 0, 0, 0};
            if (quad == 0) {
                a[0] = (short)f2bf(rw[pt][0].x); a[1] = (short)f2bf(rw[pt][0].y);
                a[2] = (short)f2bf(rw[pt][1].x); a[3] = (short)f2bf(rw[pt][1].y);
                a[4] = (short)f2bf(rw[pt][2].x); a[5] = (short)f2bf(rw[pt][2].y);
                a[6] = (short)f2bf(rw[pt][3].x); a[7] = (short)f2bf(rw[pt][3].y);
            } else if (quad == 1) {
                a[0] = (short)f2bf(rw[pt][0].x); a[1] = (short)f2bf(rw[pt][0].y);
            }
            anb[pt] = a;
        }

        // ---- issue it+1's idx + raw loads (older than WB loads -> free drain) ----
        int idxv_n = 0;
        if (more && lane < 32) idxv_n = nidx[(pp0 + 2) * KNB + lane];
        if (more) {
            #pragma unroll
            for (int pt = 0; pt < 2; ++pt) {
                const float* rp = raw + (size_t)(pp0 + 2 + pt) * (KNB * CR) + l15 * CR;
                if (quad == 0) {
                    rw[pt][0] = *(const float2*)(rp + 0);
                    rw[pt][1] = *(const float2*)(rp + 2);
                    rw[pt][2] = *(const float2*)(rp + 4);
                    rw[pt][3] = *(const float2*)(rp + 6);
                } else if (quad == 1) {
                    rw[pt][0] = *(const float2*)(rp + 8);
                }
            }
        }

        // ---- nb-MLP: per-tile WNB frag (L1-hit) -> two MFMAs ----
        float nbC[2][4][4];
        #pragma unroll
        for (int n0 = 0; n0 < 4; ++n0) {
            const bf16x8 bw = *(const bf16x8*)(ws + WS_WNB + ((n0 * 64 + lane) << 4));
            f32x4 c0 = {0.f, 0.f, 0.f, 0.f};
            f32x4 c1 = {0.f, 0.f, 0.f, 0.f};
            c0 = __builtin_amdgcn_mfma_f32_16x16x32_bf16(anb[0], bw, c0, 0, 0, 0);
            c1 = __builtin_amdgcn_mfma_f32_16x16x32_bf16(anb[1], bw, c1, 0, 0, 0);
            #pragma unroll
            for (int r = 0; r < 4; ++r) {
                const float x0 = lrelu(c0[r] + binb[n0]);
                const float x1 = lrelu(c1[r] + binb[n0]);
                nbC[0][n0][r] = x0;
                nbC[1][n0][r] = x1;
                feaA[0][quad * 4 + r][64 + n0 * 16 + l15] = f2bf(x0);
                feaA[1][quad * 4 + r][64 + n0 * 16 + l15] = f2bf(x1);
            }
        }

        // ---- gather writes (gv prefetched last iter; vmcnt window was phase 2) ----
        #pragma unroll
        for (int pt = 0; pt < 2; ++pt)
            #pragma unroll
            for (int i = 0; i < 4; ++i)
                *(uint2*)&feaA[pt][i * 4 + quad][l15 * 4] = gv[pt][i];

        // ---- attn A-frags for both pts ----
        bf16x8 A[2][4];
        #pragma unroll
        for (int pt = 0; pt < 2; ++pt)
            #pragma unroll
            for (int s = 0; s < 4; ++s)
                A[pt][s] = *(const bf16x8*)&feaA[pt][l15][s * 32 + quad * 8];

        // ---- phase 2: 8 d-tiles, ONE wb set -> TWO independent MFMA chains ----
        #pragma unroll
        for (int n0 = 0; n0 < 8; ++n0) {
            const bf16x8 wb0 = *(const bf16x8*)(wbp + (n0 * 4 + 0) * 1024);
            const bf16x8 wb1 = *(const bf16x8*)(wbp + (n0 * 4 + 1) * 1024);
            const bf16x8 wb2 = *(const bf16x8*)(wbp + (n0 * 4 + 2) * 1024);
            const bf16x8 wb3 = *(const bf16x8*)(wbp + (n0 * 4 + 3) * 1024);
            f32x4 c0 = {0.f, 0.f, 0.f, 0.f};
            f32x4 c1 = {0.f, 0.f, 0.f, 0.f};
            c0 = __builtin_amdgcn_mfma_f32_16x16x32_bf16(A[0][0], wb0, c0, 0, 0, 0);
            c1 = __builtin_amdgcn_mfma_f32_16x16x32_bf16(A[1][0], wb0, c1, 0, 0, 0);
            c0 = __builtin_amdgcn_mfma_f32_16x16x32_bf16(A[0][1], wb1, c0, 0, 0, 0);
            c1 = __builtin_amdgcn_mfma_f32_16x16x32_bf16(A[1][1], wb1, c1, 0, 0, 0);
            c0 = __builtin_amdgcn_mfma_f32_16x16x32_bf16(A[0][2], wb2, c0, 0, 0, 0);
            c1 = __builtin_amdgcn_mfma_f32_16x16x32_bf16(A[1][2], wb2, c1, 0, 0, 0);
            c0 = __builtin_amdgcn_mfma_f32_16x16x32_bf16(A[0][3], wb3, c0, 0, 0, 0);
            c1 = __builtin_amdgcn_mfma_f32_16x16x32_bf16(A[1][3], wb3, c1, 0, 0, 0);

            const float e00 = __builtin_amdgcn_exp2f(c0[0]);
            const float e01 = __builtin_amdgcn_exp2f(c0[1]);
            const float e02 = __builtin_amdgcn_exp2f(c0[2]);
            const float e03 = __builtin_amdgcn_exp2f(c0[3]);
            const float e10 = __builtin_amdgcn_exp2f(c1[0]);
            const float e11 = __builtin_amdgcn_exp2f(c1[1]);
            const float e12 = __builtin_amdgcn_exp2f(c1[2]);
            const float e13 = __builtin_amdgcn_exp2f(c1[3]);
            float den0 = e00 + e01 + e02 + e03;
            float den1 = e10 + e11 + e12 + e13;
            float num0, num1;
            if (n0 < 4) {
                num0 = e00 * bf2f(feaA[0][quad * 4 + 0][n0 * 16 + l15])
                     + e01 * bf2f(feaA[0][quad * 4 + 1][n0 * 16 + l15])
                     + e02 * bf2f(feaA[0][quad * 4 + 2][n0 * 16 + l15])
                     + e03 * bf2f(feaA[0][quad * 4 + 3][n0 * 16 + l15]);
                num1 = e10 * bf2f(feaA[1][quad * 4 + 0][n0 * 16 + l15])
                     + e11 * bf2f(feaA[1][quad * 4 + 1][n0 * 16 + l15])
                     + e12 * bf2f(feaA[1][quad * 4 + 2][n0 * 16 + l15])
                     + e13 * bf2f(feaA[1][quad * 4 + 3][n0 * 16 + l15]);
            } else {
                num0 = e00 * nbC[0][n0 - 4][0] + e01 * nbC[0][n0 - 4][1]
                     + e02 * nbC[0][n0 - 4][2] + e03 * nbC[0][n0 - 4][3];
                num1 = e10 * nbC[1][n0 - 4][0] + e11 * nbC[1][n0 - 4][1]
                     + e12 * nbC[1][n0 - 4][2] + e13 * nbC[1][n0 - 4][3];
            }
            num0 += __shfl_xor(num0, 16, 64);
            den0 += __shfl_xor(den0, 16, 64);
            num1 += __shfl_xor(num1, 16, 64);
            den1 += __shfl_xor(den1, 16, 64);
            num0 += __shfl_xor(num0, 32, 64);
            den0 += __shfl_xor(den0, 32, 64);
            num1 += __shfl_xor(num1, 32, 64);
            den1 += __shfl_xor(den1, 32, 64);
            const float pp0v = __fdividef(num0, den0);
            const float pp1v = __fdividef(num1, den1);
            if (quad == 0) {
                pooledA[it * 2 + 0][n0 * 16 + l15] = f2bf(pp0v);
                pooledA[it * 2 + 1][n0 * 16 + l15] = f2bf(pp1v);
            }
        }

        // ---- prefetch it+1's gathers straight into gv (dead since writes) ----
        if (more) {
            #pragma unroll
            for (int pt = 0; pt < 2; ++pt)
                #pragma unroll
                for (int i = 0; i < 4; ++i) {
                    const int ni = __shfl(idxv_n, pt * 16 + i * 4 + quad, 64);
                    gv[pt][i] = *(const uint2*)&feaT[(size_t)((b << 16) + ni) * CIN + l15 * 4];
                }
            idxv = idxv_n;
        }
    }

    // ---- fused phase 3: out = lrelu([pooled|feat] @ W3hat + bias3), M=16 ----
    bf16x8 A3[6];
    #pragma unroll
    for (int s = 0; s < 6; ++s)
        A3[s] = *(const bf16x8*)&pooledA[l15][s * 32 + quad * 8];
    #pragma unroll
    for (int t = 0; t < 8; ++t) {
        f32x4 c = {0.f, 0.f, 0.f, 0.f};
        #pragma unroll
        for (int s = 0; s < 6; ++s) {
            const bf16x8 bw = *(const bf16x8*)(ws + WS_W3 + (((t * 6 + s) * 64 + lane) << 4));
            c = __builtin_amdgcn_mfma_f32_16x16x32_bf16(A3[s], bw, c, 0, 0, 0);
        }
        const float bz = ((const float*)(ws + WS_B3))[t * 16 + l15];
        #pragma unroll
        for (int r = 0; r < 4; ++r)
            out[(size_t)(p0 + quad * 4 + r) * COUT + t * 16 + l15] = lrelu(c[r] + bz);
    }
}

// ---------------------------------------------------------------------------
// Fallback main (exact r5 kernel, known 270 us): used if ws too small.
// ---------------------------------------------------------------------------
__global__ __launch_bounds__(256, 2) void lfa_main_f32(
    fp feature, fp raw, const int* __restrict__ nidx,
    const unsigned char* __restrict__ ws, float* __restrict__ out)
{
    __shared__ __align__(16) unsigned short feaA[4][16][136];
    __shared__ __align__(16) unsigned short pooledA[4][16][200];

    const int tid  = threadIdx.x;
    const int w    = tid >> 6;
    const int lane = tid & 63;
    const int quad = lane >> 4;
    const int l15  = lane & 15;
    const int p0   = (blockIdx.x * 4 + w) * 16;
    const int b    = p0 >> 16;

    bf16x8 WB[8][4];
    #pragma unroll
    for (int n0 = 0; n0 < 8; ++n0)
        #pragma unroll
        for (int s = 0; s < 4; ++s)
            WB[n0][s] = *(const bf16x8*)(ws + WS_WB + (((n0 * 4 + s) * 64 + lane) << 4));

    float binb[4];
    #pragma unroll
    for (int j = 0; j < 4; ++j)
        binb[j] = ((const float*)(ws + WS_BNB))[j * 16 + l15];

    #pragma unroll 1
    for (int it = 0; it < 8; ++it) {
        const int pp0 = p0 + it * 2;

        int idxv = 0;
        if (lane < 32) idxv = nidx[pp0 * KNB + lane];

        if (lane < 32) {
            const int pt = lane >> 4, c4 = l15 * 4;
            const float4 cf = *(const float4*)&feature[(size_t)(pp0 + pt) * CIN + c4];
            uint2 pk; pk.x = pack2(cf.x, cf.y); pk.y = pack2(cf.z, cf.w);
            *(uint2*)&pooledA[w][it * 2 + pt][CCAT + c4] = pk;
        }

        #pragma unroll
        for (int pt = 0; pt < 2; ++pt) {
            const int p = pp0 + pt;

            float4 gv[4];
            #pragma unroll
            for (int i = 0; i < 4; ++i) {
                const int ni = __shfl(idxv, pt * 16 + i * 4 + quad, 64);
                gv[i] = *(const float4*)&feature[(size_t)((b << 16) + ni) * CIN + l15 * 4];
            }

            bf16x8 anb = {0, 0, 0, 0, 0, 0, 0, 0};
            {
                const float* rp = raw + (size_t)p * (KNB * CR) + l15 * CR;
                if (quad == 0) {
                    const float2 r0 = *(const float2*)(rp + 0);
                    const float2 r1 = *(const float2*)(rp + 2);
                    const float2 r2 = *(const float2*)(rp + 4);
                    const float2 r3 = *(const float2*)(rp + 6);
                    anb[0] = (short)f2bf(r0.x); anb[1] = (short)f2bf(r0.y);
                    anb[2] = (short)f2bf(r1.x); anb[3] = (short)f2bf(r1.y);
                    anb[4] = (short)f2bf(r2.x); anb[5] = (short)f2bf(r2.y);
                    anb[6] = (short)f2bf(r3.x); anb[7] = (short)f2bf(r3.y);
                } else if (quad == 1) {
                    const float2 r4 = *(const float2*)(rp + 8);
                    anb[0] = (short)f2bf(r4.x); anb[1] = (short)f2bf(r4.y);
                }
            }

            float nbC[4][4];
            #pragma unroll
            for (int n0 = 0; n0 < 4; ++n0) {
                const bf16x8 bw = *(const bf16x8*)(ws + WS_WNB + ((n0 * 64 + lane) << 4));
                f32x4 c = {0.f, 0.f, 0.f, 0.f};
                c = __builtin_amdgcn_mfma_f32_16x16x32_bf16(anb, bw, c, 0, 0, 0);
                #pragma unroll
                for (int r = 0; r < 4; ++r) {
                    const float x = lrelu(c[r] + binb[n0]);
                    nbC[n0][r] = x;
                    feaA[w][quad * 4 + r][64 + n0 * 16 + l15] = f2bf(x);
                }
            }

            #pragma unroll
            for (int i = 0; i < 4; ++i) {
                uint2 pk; pk.x = pack2(gv[i].x, gv[i].y); pk.y = pack2(gv[i].z, gv[i].w);
                *(uint2*)&feaA[w][i * 4 + quad][l15 * 4] = pk;
            }

            bf16x8 A[4];
            #pragma unroll
            for (int s = 0; s < 4; ++s)
                A[s] = *(const bf16x8*)&feaA[w][l15][s * 32 + quad * 8];

            #pragma unroll
            for (int n0 = 0; n0 < 8; ++n0) {
                f32x4 c = {0.f, 0.f, 0.f, 0.f};
                #pragma unroll
                for (int s = 0; s < 4; ++s)
                    c = __builtin_amdgcn_mfma_f32_16x16x32_bf16(A[s], WB[n0][s], c, 0, 0, 0);
                const float e0 = __builtin_amdgcn_exp2f(c[0]);
                const float e1 = __builtin_amdgcn_exp2f(c[1]);
                const float e2 = __builtin_amdgcn_exp2f(c[2]);
                const float e3 = __builtin_amdgcn_exp2f(c[3]);
                float den = e0 + e1 + e2 + e3;
                float num;
                if (n0 < 4) {
                    num = e0 * bf2f(feaA[w][quad * 4 + 0][n0 * 16 + l15])
                        + e1 * bf2f(feaA[w][quad * 4 + 1][n0 * 16 + l15])
                        + e2 * bf2f(feaA[w][quad * 4 + 2][n0 * 16 + l15])
                        + e3 * bf2f(feaA[w][quad * 4 + 3][n0 * 16 + l15]);
                } else {
                    num = e0 * nbC[n0 - 4][0] + e1 * nbC[n0 - 4][1]
                        + e2 * nbC[n0 - 4][2] + e3 * nbC[n0 - 4][3];
                }
                num += __shfl_xor(num, 16, 64);
                den += __shfl_xor(den, 16, 64);
                num += __shfl_xor(num, 32, 64);
                den += __shfl_xor(den, 32, 64);
                const float pp = __fdividef(num, den);
                if (quad == 0)
                    pooledA[w][it * 2 + pt][n0 * 16 + l15] = f2bf(pp);
            }
        }
    }

    bf16x8 A3[6];
    #pragma unroll
    for (int s = 0; s < 6; ++s)
        A3[s] = *(const bf16x8*)&pooledA[w][l15][s * 32 + quad * 8];
    #pragma unroll
    for (int t = 0; t < 8; ++t) {
        f32x4 c = {0.f, 0.f, 0.f, 0.f};
        #pragma unroll
        for (int s = 0; s < 6; ++s) {
            const bf16x8 bw = *(const bf16x8*)(ws + WS_W3 + (((t * 6 + s) * 64 + lane) << 4));
            c = __builtin_amdgcn_mfma_f32_16x16x32_bf16(A3[s], bw, c, 0, 0, 0);
        }
        const float bz = ((const float*)(ws + WS_B3))[t * 16 + l15];
        #pragma unroll
        for (int r = 0; r < 4; ++r)
            out[(size_t)(p0 + quad * 4 + r) * COUT + t * 16 + l15] = lrelu(c[r] + bz);
    }
}

extern "C" void kernel_launch(void* const* d_in, const int* in_sizes, int n_in,
                              void* d_out, int out_size, void* d_ws, size_t ws_size,
                              hipStream_t stream)
{
    fp feature = (fp)d_in[1];
    fp raw     = (fp)d_in[2];
    const int* nidx = (const int*)d_in[3];
    fp W_nb = (fp)d_in[4],  b_nb = (fp)d_in[5],  g_nb = (fp)d_in[6];
    fp be_nb = (fp)d_in[7], m_nb = (fp)d_in[8],  v_nb = (fp)d_in[9];
    fp W_attn = (fp)d_in[10];
    fp W_out = (fp)d_in[11], b_out = (fp)d_in[12], g_out = (fp)d_in[13];
    fp be_out = (fp)d_in[14], m_out = (fp)d_in[15], v_out = (fp)d_in[16];
    fp W_sc = (fp)d_in[17], b_sc = (fp)d_in[18], g_sc = (fp)d_in[19];
    fp be_sc = (fp)d_in[20], m_sc = (fp)d_in[21], v_sc = (fp)d_in[22];

    hipLaunchKernelGGL(lfa_prep, dim3(22), dim3(256), 0, stream,
                       W_nb, b_nb, g_nb, be_nb, m_nb, v_nb,
                       W_attn,
                       W_out, b_out, g_out, be_out, m_out, v_out,
                       W_sc, b_sc, g_sc, be_sc, m_sc, v_sc,
                       (unsigned char*)d_ws);

    const size_t need = (size_t)WS_FEA + (size_t)NPTS * CIN * 2;
    if (ws_size >= need) {
        hipLaunchKernelGGL(lfa_prep_fea, dim3(4096), dim3(256), 0, stream,
                           feature, (unsigned char*)d_ws);
        hipLaunchKernelGGL(lfa_main_bf16, dim3(8192), dim3(64), 0, stream,
                           raw, nidx, (const unsigned char*)d_ws, (float*)d_out);
    } else {
        hipLaunchKernelGGL(lfa_main_f32, dim3(2048), dim3(256), 0, stream,
                           feature, raw, nidx,
                           (const unsigned char*)d_ws, (float*)d_out);
    }
}

// Round 9
// 457.302 us; speedup vs baseline: 1.0922x; 1.0922x over previous
//
#include <hip/hip_runtime.h>

// LocalFeatureAggregation — round 12: zero-VGPR gather prefetch (global_load_lds).
//  * r11 lesson (the occupancy law): waves/SIMD cap halves at VGPR {64,128,256}
//    (m69). 128->144 VGPR halved occupancy (21.7->11.4%) and dur 247->343us.
//    HARD RULE: VGPR must stay <=128; register-costing prefetch is dead.
//  * This round: r9 structure (best, 247us) + gathers staged one iteration
//    ahead via global_load_lds (NO dest registers; frees r9's gv[2][4], -16).
//    feaA split: feaG[2dbuf][2pt][16][64] staged linearly by 4x width-16
//    global_load_lds; feaN[2][16][64] for nb-MLP outputs. Both halves use the
//    16B-chunk XOR swizzle (chunk ^ row&7) with PRE-SWIZZLED global source
//    (rule #21 both-sides pattern) -> ds_read_b128 A-frags 2-way (free).
//  * Staged loads issued mid-phase2 (after n0=3) using idx(it+1) loaded at
//    iteration top -> ~1500cy flight window; consumed after explicit
//    s_waitcnt vmcnt(0) (compiler doesn't track global_load_lds->ds_read).
//  * Raw loads stay JIT exactly as r9 (staging them = r10/r11's reg cost).
//  * Gates: VGPR <=128; WRITE ~65.5MB; FETCH ~146MB.
// Requires ws_size >= 16864256 for the fast path (>= 86784 for fallback).

#define KNB   16
#define CR    10
#define CIN   64
#define CCAT  128
#define COUT  128
#define NPTS  131072
#define EPS   1e-5f
#define LOG2E 1.4426950408889634f

// d_ws layout (bytes)
#define WS_WB   0        // W_attn B-frags (pre-scaled by log2e): 2048 * 16 B = 32768
#define WS_W3   32768    // [W_out;W_sc] BN-folded B-frags: 3072 * 16 B = 49152
#define WS_WNB  81920    // W_nb BN-folded B-frags (K padded to 32): 256 * 16 B = 4096
#define WS_B3   86016    // bias3[128] fp32
#define WS_BNB  86528    // binb[64] fp32   -> 86784
#define WS_FEA  87040    // bf16 feature table [NPTS][CIN]: 16777216 B -> total 16864256

typedef const float* fp;
typedef short bf16x8 __attribute__((ext_vector_type(8)));
typedef float f32x4  __attribute__((ext_vector_type(4)));
typedef __bf16 bf16x2 __attribute__((ext_vector_type(2)));

__device__ __forceinline__ unsigned short f2bf(float x) {
    return __builtin_bit_cast(unsigned short, (__bf16)x);     // HW RNE cvt
}
__device__ __forceinline__ unsigned int pack2(float a, float b) {
    bf16x2 v; v.x = (__bf16)a; v.y = (__bf16)b;               // v_cvt_pk_bf16_f32
    return __builtin_bit_cast(unsigned int, v);
}
__device__ __forceinline__ float bf2f(unsigned short h) {
    return __uint_as_float(((unsigned int)h) << 16);
}
__device__ __forceinline__ float lrelu(float x) { return fmaxf(x, 0.2f * x); }

// swizzled access into a [16][64]-bf16 half-matrix (16B-chunk XOR row&7).
// c = bf16 column 0..63. For 16B frag reads use c = s*32+quad*8 (c&7 == 0).
__device__ __forceinline__ unsigned short* swzp(unsigned short (*h)[64], int row, int c) {
    const int cg  = c >> 3;                                   // chunk 0..7
    const int off = row * 128 + (((cg ^ (row & 7)) << 4) | ((c & 7) << 1));
    return (unsigned short*)((unsigned char*)h + off);
}
__device__ __forceinline__ const unsigned short* swzc(const unsigned short (*h)[64], int row, int c) {
    const int cg  = c >> 3;
    const int off = row * 128 + (((cg ^ (row & 7)) << 4) | ((c & 7) << 1));
    return (const unsigned short*)((const unsigned char*)h + off);
}

// ---------------------------------------------------------------------------
// Prep: build all weight-fragment tables in d_ws.
// ---------------------------------------------------------------------------
__global__ __launch_bounds__(256) void lfa_prep(
    fp W_nb, fp b_nb, fp g_nb, fp be_nb, fp m_nb, fp v_nb,
    fp W_attn,
    fp W_out, fp b_out, fp g_out, fp be_out, fp m_out, fp v_out,
    fp W_sc,  fp b_sc,  fp g_sc,  fp be_sc,  fp m_sc,  fp v_sc,
    unsigned char* __restrict__ ws)
{
    const int t = blockIdx.x * 256 + threadIdx.x;
    if (t < 2048) {                                   // W_attn frags (x log2e)
        const int n0 = t >> 8, s = (t >> 6) & 3, ln = t & 63;
        const int n = (n0 << 4) + (ln & 15);
        unsigned int v[4];
        #pragma unroll
        for (int jj = 0; jj < 4; ++jj) {
            const int k = (s << 5) + ((ln >> 4) << 3) + jj * 2;
            v[jj] = pack2(W_attn[k * CCAT + n] * LOG2E,
                          W_attn[(k + 1) * CCAT + n] * LOG2E);
        }
        *(uint4*)(ws + WS_WB + t * 16) = make_uint4(v[0], v[1], v[2], v[3]);
    } else if (t < 5120) {                            // [W_out;W_sc] BN-folded frags
        const int e = t - 2048;
        const int t8 = e / 384, rem = e % 384, s = rem >> 6, ln = rem & 63;
        const int d = (t8 << 4) + (ln & 15);
        const float so = g_out[d] * rsqrtf(v_out[d] + EPS);
        const float ss = g_sc[d]  * rsqrtf(v_sc[d]  + EPS);
        unsigned int v[4];
        #pragma unroll
        for (int jj = 0; jj < 4; ++jj) {
            float a[2];
            #pragma unroll
            for (int h = 0; h < 2; ++h) {
                const int k = (s << 5) + ((ln >> 4) << 3) + jj * 2 + h;   // 0..191
                a[h] = (k < CCAT) ? W_out[k * COUT + d] * so
                                  : W_sc[(k - CCAT) * COUT + d] * ss;
            }
            v[jj] = pack2(a[0], a[1]);
        }
        *(uint4*)(ws + WS_W3 + e * 16) = make_uint4(v[0], v[1], v[2], v[3]);
    } else if (t < 5376) {                            // W_nb BN-prescaled frags
        const int e = t - 5120;
        const int n0 = e >> 6, ln = e & 63;
        const int n = (n0 << 4) + (ln & 15);
        const float sn = g_nb[n] * rsqrtf(v_nb[n] + EPS);
        unsigned int v[4];
        #pragma unroll
        for (int jj = 0; jj < 4; ++jj) {
            float a[2];
            #pragma unroll
            for (int h = 0; h < 2; ++h) {
                const int k = ((ln >> 4) << 3) + jj * 2 + h;
                a[h] = (k < CR) ? W_nb[k * 64 + n] * sn : 0.f;
            }
            v[jj] = pack2(a[0], a[1]);
        }
        *(uint4*)(ws + WS_WNB + e * 16) = make_uint4(v[0], v[1], v[2], v[3]);
    } else if (t < 5504) {                            // bias3
        const int d = t - 5376;
        const float so = g_out[d] * rsqrtf(v_out[d] + EPS);
        const float ss = g_sc[d]  * rsqrtf(v_sc[d]  + EPS);
        ((float*)(ws + WS_B3))[d] =
              (b_out[d] - m_out[d]) * so + be_out[d]
            + (b_sc[d]  - m_sc[d])  * ss + be_sc[d];
    } else if (t < 5568) {                            // nb bias
        const int d = t - 5504;
        const float sn = g_nb[d] * rsqrtf(v_nb[d] + EPS);
        ((float*)(ws + WS_BNB))[d] = (b_nb[d] - m_nb[d]) * sn + be_nb[d];
    }
}

// ---------------------------------------------------------------------------
// Prep 2: bf16 feature table [NPTS][CIN] into ws+WS_FEA (8 ch per thread).
// ---------------------------------------------------------------------------
__global__ __launch_bounds__(256) void lfa_prep_fea(
    fp feature, unsigned char* __restrict__ ws)
{
    const int t = blockIdx.x * 256 + threadIdx.x;
    const size_t idx = (size_t)t * 8;
    if (idx < (size_t)NPTS * CIN) {
        const float4 f0 = *(const float4*)&feature[idx];
        const float4 f1 = *(const float4*)&feature[idx + 4];
        uint4 o;
        o.x = pack2(f0.x, f0.y); o.y = pack2(f0.z, f0.w);
        o.z = pack2(f1.x, f1.y); o.w = pack2(f1.z, f1.w);
        *(uint4*)(ws + WS_FEA + idx * 2) = o;
    }
}

// ---------------------------------------------------------------------------
// Main (fast path): 1-wave blocks, r9 point-paired loop + LDS-staged gathers.
// 8192 blocks x 64 thr, 16 pts/block. LDS = 18688 B. VGPR target <=128.
// ---------------------------------------------------------------------------
__global__ __launch_bounds__(64, 2) void lfa_main_bf16(
    fp raw, const int* __restrict__ nidx,
    const unsigned char* __restrict__ ws, float* __restrict__ out)
{
    __shared__ __align__(16) unsigned short feaG[2][2][16][64];  // 8192 B (dbuf x pt)
    __shared__ __align__(16) unsigned short feaN[2][16][64];     // 4096 B (pt)
    __shared__ __align__(16) unsigned short pooledA[16][200];    // 6400 B

    const int lane = threadIdx.x;              // 0..63
    const int quad = lane >> 4;
    const int l15  = lane & 15;
    const int p0   = blockIdx.x * 16;          // block's 16 points
    const int b    = p0 >> 16;                 // batch (16-pt range never straddles)

    const unsigned short* feaT = (const unsigned short*)(ws + WS_FEA);
    const unsigned char*  wbp  = ws + WS_WB + ((size_t)lane << 4);

    // lane's pre-swizzled source chunk offset: chunk (l&7) at dest row i*8+(l>>3)
    // must carry global chunk (l&7)^(row&7) = (l&7)^(l>>3).
    const int srcswz = ((lane & 7) ^ (lane >> 3)) << 4;
    const int rowsh  = lane >> 3;              // dest row within 8-row group

    // ---- hoisted: center rows for ALL 16 points -> pooledA[:,128..191] ----
    #pragma unroll
    for (int j = 0; j < 4; ++j) {
        const int e   = j * 64 + lane;         // 0..255
        const int row = e >> 4, c4 = (e & 15) * 4;
        const uint2 cf = *(const uint2*)&feaT[(size_t)(p0 + row) * CIN + c4];
        *(uint2*)&pooledA[row][CCAT + c4] = cf;
    }

    float binb[4];
    #pragma unroll
    for (int j = 0; j < 4; ++j)
        binb[j] = ((const float*)(ws + WS_BNB))[j * 16 + l15];

    // ---- prologue: idx(0) + stage it=0 gathers into feaG[0] ----
    int idxv = 0;
    if (lane < 32) idxv = nidx[p0 * KNB + lane];
    #pragma unroll
    for (int pt = 0; pt < 2; ++pt)
        #pragma unroll
        for (int i = 0; i < 2; ++i) {
            const int ni = __shfl(idxv, pt * 16 + i * 8 + rowsh, 64);
            const unsigned char* src = (const unsigned char*)feaT
                + (((size_t)((b << 16) + ni)) << 7) + srcswz;
            __builtin_amdgcn_global_load_lds(
                (__attribute__((address_space(1))) const void*)src,
                (__attribute__((address_space(3))) void*)
                    ((unsigned char*)&feaG[0][pt][0][0] + i * 1024),
                16, 0, 0);
        }

    int cur = 0;
    #pragma unroll 1
    for (int it = 0; it < 8; ++it) {
        const int  pp0  = p0 + it * 2;
        const bool more = (it < 7);

        // ---- idx for it+1 (consumed mid-phase2 for staging) ----
        int idxn = 0;
        if (more && lane < 32) idxn = nidx[(pp0 + 2) * KNB + lane];

        // ---- raw JIT loads + anb pack (r9 pattern, short-lived regs) ----
        bf16x8 anb[2];
        #pragma unroll
        for (int pt = 0; pt < 2; ++pt) {
            bf16x8 a = {0, 0, 0, 0, 0, 0, 0, 0};
            const float* rp = raw + (size_t)(pp0 + pt) * (KNB * CR) + l15 * CR;
            if (quad == 0) {
                const float2 r0 = *(const float2*)(rp + 0);
                const float2 r1 = *(const float2*)(rp + 2);
                const float2 r2 = *(const float2*)(rp + 4);
                const float2 r3 = *(const float2*)(rp + 6);
                a[0] = (short)f2bf(r0.x); a[1] = (short)f2bf(r0.y);
                a[2] = (short)f2bf(r1.x); a[3] = (short)f2bf(r1.y);
                a[4] = (short)f2bf(r2.x); a[5] = (short)f2bf(r2.y);
                a[6] = (short)f2bf(r3.x); a[7] = (short)f2bf(r3.y);
            } else if (quad == 1) {
                const float2 r4 = *(const float2*)(rp + 8);
                a[0] = (short)f2bf(r4.x); a[1] = (short)f2bf(r4.y);
            }
            anb[pt] = a;
        }

        // ---- nb-MLP: per-tile WNB frag (L1-hit) -> two MFMAs -> feaN (swz) ----
        float nbC[2][4][4];
        #pragma unroll
        for (int n0 = 0; n0 < 4; ++n0) {
            const bf16x8 bw = *(const bf16x8*)(ws + WS_WNB + ((n0 * 64 + lane) << 4));
            f32x4 c0 = {0.f, 0.f, 0.f, 0.f};
            f32x4 c1 = {0.f, 0.f, 0.f, 0.f};
            c0 = __builtin_amdgcn_mfma_f32_16x16x32_bf16(anb[0], bw, c0, 0, 0, 0);
            c1 = __builtin_amdgcn_mfma_f32_16x16x32_bf16(anb[1], bw, c1, 0, 0, 0);
            #pragma unroll
            for (int r = 0; r < 4; ++r) {
                const float x0 = lrelu(c0[r] + binb[n0]);
                const float x1 = lrelu(c1[r] + binb[n0]);
                nbC[0][n0][r] = x0;
                nbC[1][n0][r] = x1;
                *swzp(feaN[0], quad * 4 + r, n0 * 16 + l15) = f2bf(x0);
                *swzp(feaN[1], quad * 4 + r, n0 * 16 + l15) = f2bf(x1);
            }
        }

        // ---- staged gathers for THIS iteration are now needed ----
        asm volatile("s_waitcnt vmcnt(0)" ::: "memory");

        // ---- attn A-frags: s=0,1 from feaG[cur] (swz), s=2,3 from feaN (swz) ----
        bf16x8 A[2][4];
        #pragma unroll
        for (int pt = 0; pt < 2; ++pt) {
            A[pt][0] = *(const bf16x8*)swzc(feaG[cur][pt], l15, 0  + quad * 8);
            A[pt][1] = *(const bf16x8*)swzc(feaG[cur][pt], l15, 32 + quad * 8);
            A[pt][2] = *(const bf16x8*)swzc(feaN[pt],      l15, 0  + quad * 8);
            A[pt][3] = *(const bf16x8*)swzc(feaN[pt],      l15, 32 + quad * 8);
        }

        // ---- phase 2: 8 d-tiles, ONE wb set -> TWO independent MFMA chains ----
        #pragma unroll
        for (int n0 = 0; n0 < 8; ++n0) {
            const bf16x8 wb0 = *(const bf16x8*)(wbp + (n0 * 4 + 0) * 1024);
            const bf16x8 wb1 = *(const bf16x8*)(wbp + (n0 * 4 + 1) * 1024);
            const bf16x8 wb2 = *(const bf16x8*)(wbp + (n0 * 4 + 2) * 1024);
            const bf16x8 wb3 = *(const bf16x8*)(wbp + (n0 * 4 + 3) * 1024);
            f32x4 c0 = {0.f, 0.f, 0.f, 0.f};
            f32x4 c1 = {0.f, 0.f, 0.f, 0.f};
            c0 = __builtin_amdgcn_mfma_f32_16x16x32_bf16(A[0][0], wb0, c0, 0, 0, 0);
            c1 = __builtin_amdgcn_mfma_f32_16x16x32_bf16(A[1][0], wb0, c1, 0, 0, 0);
            c0 = __builtin_amdgcn_mfma_f32_16x16x32_bf16(A[0][1], wb1, c0, 0, 0, 0);
            c1 = __builtin_amdgcn_mfma_f32_16x16x32_bf16(A[1][1], wb1, c1, 0, 0, 0);
            c0 = __builtin_amdgcn_mfma_f32_16x16x32_bf16(A[0][2], wb2, c0, 0, 0, 0);
            c1 = __builtin_amdgcn_mfma_f32_16x16x32_bf16(A[1][2], wb2, c1, 0, 0, 0);
            c0 = __builtin_amdgcn_mfma_f32_16x16x32_bf16(A[0][3], wb3, c0, 0, 0, 0);
            c1 = __builtin_amdgcn_mfma_f32_16x16x32_bf16(A[1][3], wb3, c1, 0, 0, 0);

            // mid-phase2: issue it+1's staged gathers (zero-VGPR prefetch).
            // Younger than remaining WB loads -> nothing here waits on them;
            // flight window = n0 4..7 + next top raw stall (~1500cy).
            if (n0 == 3 && more) {
                #pragma unroll
                for (int pt = 0; pt < 2; ++pt)
                    #pragma unroll
                    for (int i = 0; i < 2; ++i) {
                        const int ni = __shfl(idxn, pt * 16 + i * 8 + rowsh, 64);
                        const unsigned char* src = (const unsigned char*)feaT
                            + (((size_t)((b << 16) + ni)) << 7) + srcswz;
                        __builtin_amdgcn_global_load_lds(
                            (__attribute__((address_space(1))) const void*)src,
                            (__attribute__((address_space(3))) void*)
                                ((unsigned char*)&feaG[cur ^ 1][pt][0][0] + i * 1024),
                            16, 0, 0);
                    }
            }

            const float e00 = __builtin_amdgcn_exp2f(c0[0]);
            const float e01 = __builtin_amdgcn_exp2f(c0[1]);
            const float e02 = __builtin_amdgcn_exp2f(c0[2]);
            const float e03 = __builtin_amdgcn_exp2f(c0[3]);
            const float e10 = __builtin_amdgcn_exp2f(c1[0]);
            const float e11 = __builtin_amdgcn_exp2f(c1[1]);
            const float e12 = __builtin_amdgcn_exp2f(c1[2]);
            const float e13 = __builtin_amdgcn_exp2f(c1[3]);
            float den0 = e00 + e01 + e02 + e03;
            float den1 = e10 + e11 + e12 + e13;
            float num0, num1;
            if (n0 < 4) {
                num0 = e00 * bf2f(*swzc(feaG[cur][0], quad * 4 + 0, n0 * 16 + l15))
                     + e01 * bf2f(*swzc(feaG[cur][0], quad * 4 + 1, n0 * 16 + l15))
                     + e02 * bf2f(*swzc(feaG[cur][0], quad * 4 + 2, n0 * 16 + l15))
                     + e03 * bf2f(*swzc(feaG[cur][0], quad * 4 + 3, n0 * 16 + l15));
                num1 = e10 * bf2f(*swzc(feaG[cur][1], quad * 4 + 0, n0 * 16 + l15))
                     + e11 * bf2f(*swzc(feaG[cur][1], quad * 4 + 1, n0 * 16 + l15))
                     + e12 * bf2f(*swzc(feaG[cur][1], quad * 4 + 2, n0 * 16 + l15))
                     + e13 * bf2f(*swzc(feaG[cur][1], quad * 4 + 3, n0 * 16 + l15));
            } else {
                num0 = e00 * nbC[0][n0 - 4][0] + e01 * nbC[0][n0 - 4][1]
                     + e02 * nbC[0][n0 - 4][2] + e03 * nbC[0][n0 - 4][3];
                num1 = e10 * nbC[1][n0 - 4][0] + e11 * nbC[1][n0 - 4][1]
                     + e12 * nbC[1][n0 - 4][2] + e13 * nbC[1][n0 - 4][3];
            }
            num0 += __shfl_xor(num0, 16, 64);
            den0 += __shfl_xor(den0, 16, 64);
            num1 += __shfl_xor(num1, 16, 64);
            den1 += __shfl_xor(den1, 16, 64);
            num0 += __shfl_xor(num0, 32, 64);
            den0 += __shfl_xor(den0, 32, 64);
            num1 += __shfl_xor(num1, 32, 64);
            den1 += __shfl_xor(den1, 32, 64);
            const float pp0v = __fdividef(num0, den0);
            const float pp1v = __fdividef(num1, den1);
            if (quad == 0) {
                pooledA[it * 2 + 0][n0 * 16 + l15] = f2bf(pp0v);
                pooledA[it * 2 + 1][n0 * 16 + l15] = f2bf(pp1v);
            }
        }

        cur ^= 1;
    }

    // ---- fused phase 3: out = lrelu([pooled|feat] @ W3hat + bias3), M=16 ----
    bf16x8 A3[6];
    #pragma unroll
    for (int s = 0; s < 6; ++s)
        A3[s] = *(const bf16x8*)&pooledA[l15][s * 32 + quad * 8];
    #pragma unroll
    for (int t = 0; t < 8; ++t) {
        f32x4 c = {0.f, 0.f, 0.f, 0.f};
        #pragma unroll
        for (int s = 0; s < 6; ++s) {
            const bf16x8 bw = *(const bf16x8*)(ws + WS_W3 + (((t * 6 + s) * 64 + lane) << 4));
            c = __builtin_amdgcn_mfma_f32_16x16x32_bf16(A3[s], bw, c, 0, 0, 0);
        }
        const float bz = ((const float*)(ws + WS_B3))[t * 16 + l15];
        #pragma unroll
        for (int r = 0; r < 4; ++r)
            out[(size_t)(p0 + quad * 4 + r) * COUT + t * 16 + l15] = lrelu(c[r] + bz);
    }
}

// ---------------------------------------------------------------------------
// Fallback main (exact r5 kernel, known 270 us): used if ws too small.
// ---------------------------------------------------------------------------
__global__ __launch_bounds__(256, 2) void lfa_main_f32(
    fp feature, fp raw, const int* __restrict__ nidx,
    const unsigned char* __restrict__ ws, float* __restrict__ out)
{
    __shared__ __align__(16) unsigned short feaA[4][16][136];
    __shared__ __align__(16) unsigned short pooledA[4][16][200];

    const int tid  = threadIdx.x;
    const int w    = tid >> 6;
    const int lane = tid & 63;
    const int quad = lane >> 4;
    const int l15  = lane & 15;
    const int p0   = (blockIdx.x * 4 + w) * 16;
    const int b    = p0 >> 16;

    bf16x8 WB[8][4];
    #pragma unroll
    for (int n0 = 0; n0 < 8; ++n0)
        #pragma unroll
        for (int s = 0; s < 4; ++s)
            WB[n0][s] = *(const bf16x8*)(ws + WS_WB + (((n0 * 4 + s) * 64 + lane) << 4));

    float binb[4];
    #pragma unroll
    for (int j = 0; j < 4; ++j)
        binb[j] = ((const float*)(ws + WS_BNB))[j * 16 + l15];

    #pragma unroll 1
    for (int it = 0; it < 8; ++it) {
        const int pp0 = p0 + it * 2;

        int idxv = 0;
        if (lane < 32) idxv = nidx[pp0 * KNB + lane];

        if (lane < 32) {
            const int pt = lane >> 4, c4 = l15 * 4;
            const float4 cf = *(const float4*)&feature[(size_t)(pp0 + pt) * CIN + c4];
            uint2 pk; pk.x = pack2(cf.x, cf.y); pk.y = pack2(cf.z, cf.w);
            *(uint2*)&pooledA[w][it * 2 + pt][CCAT + c4] = pk;
        }

        #pragma unroll
        for (int pt = 0; pt < 2; ++pt) {
            const int p = pp0 + pt;

            float4 gv[4];
            #pragma unroll
            for (int i = 0; i < 4; ++i) {
                const int ni = __shfl(idxv, pt * 16 + i * 4 + quad, 64);
                gv[i] = *(const float4*)&feature[(size_t)((b << 16) + ni) * CIN + l15 * 4];
            }

            bf16x8 anb = {0, 0, 0, 0, 0, 0, 0, 0};
            {
                const float* rp = raw + (size_t)p * (KNB * CR) + l15 * CR;
                if (quad == 0) {
                    const float2 r0 = *(const float2*)(rp + 0);
                    const float2 r1 = *(const float2*)(rp + 2);
                    const float2 r2 = *(const float2*)(rp + 4);
                    const float2 r3 = *(const float2*)(rp + 6);
                    anb[0] = (short)f2bf(r0.x); anb[1] = (short)f2bf(r0.y);
                    anb[2] = (short)f2bf(r1.x); anb[3] = (short)f2bf(r1.y);
                    anb[4] = (short)f2bf(r2.x); anb[5] = (short)f2bf(r2.y);
                    anb[6] = (short)f2bf(r3.x); anb[7] = (short)f2bf(r3.y);
                } else if (quad == 1) {
                    const float2 r4 = *(const float2*)(rp + 8);
                    anb[0] = (short)f2bf(r4.x); anb[1] = (short)f2bf(r4.y);
                }
            }

            float nbC[4][4];
            #pragma unroll
            for (int n0 = 0; n0 < 4; ++n0) {
                const bf16x8 bw = *(const bf16x8*)(ws + WS_WNB + ((n0 * 64 + lane) << 4));
                f32x4 c = {0.f, 0.f, 0.f, 0.f};
                c = __builtin_amdgcn_mfma_f32_16x16x32_bf16(anb, bw, c, 0, 0, 0);
                #pragma unroll
                for (int r = 0; r < 4; ++r) {
                    const float x = lrelu(c[r] + binb[n0]);
                    nbC[n0][r] = x;
                    feaA[w][quad * 4 + r][64 + n0 * 16 + l15] = f2bf(x);
                }
            }

            #pragma unroll
            for (int i = 0; i < 4; ++i) {
                uint2 pk; pk.x = pack2(gv[i].x, gv[i].y); pk.y = pack2(gv[i].z, gv[i].w);
                *(uint2*)&feaA[w][i * 4 + quad][l15 * 4] = pk;
            }

            bf16x8 A[4];
            #pragma unroll
            for (int s = 0; s < 4; ++s)
                A[s] = *(const bf16x8*)&feaA[w][l15][s * 32 + quad * 8];

            #pragma unroll
            for (int n0 = 0; n0 < 8; ++n0) {
                f32x4 c = {0.f, 0.f, 0.f, 0.f};
                #pragma unroll
                for (int s = 0; s < 4; ++s)
                    c = __builtin_amdgcn_mfma_f32_16x16x32_bf16(A[s], WB[n0][s], c, 0, 0, 0);
                const float e0 = __builtin_amdgcn_exp2f(c[0]);
                const float e1 = __builtin_amdgcn_exp2f(c[1]);
                const float e2 = __builtin_amdgcn_exp2f(c[2]);
                const float e3 = __builtin_amdgcn_exp2f(c[3]);
                float den = e0 + e1 + e2 + e3;
                float num;
                if (n0 < 4) {
                    num = e0 * bf2f(feaA[w][quad * 4 + 0][n0 * 16 + l15])
                        + e1 * bf2f(feaA[w][quad * 4 + 1][n0 * 16 + l15])
                        + e2 * bf2f(feaA[w][quad * 4 + 2][n0 * 16 + l15])
                        + e3 * bf2f(feaA[w][quad * 4 + 3][n0 * 16 + l15]);
                } else {
                    num = e0 * nbC[n0 - 4][0] + e1 * nbC[n0 - 4][1]
                        + e2 * nbC[n0 - 4][2] + e3 * nbC[n0 - 4][3];
                }
                num += __shfl_xor(num, 16, 64);
                den += __shfl_xor(den, 16, 64);
                num += __shfl_xor(num, 32, 64);
                den += __shfl_xor(den, 32, 64);
                const float pp = __fdividef(num, den);
                if (quad == 0)
                    pooledA[w][it * 2 + pt][n0 * 16 + l15] = f2bf(pp);
            }
        }
    }

    bf16x8 A3[6];
    #pragma unroll
    for (int s = 0; s < 6; ++s)
        A3[s] = *(const bf16x8*)&pooledA[w][l15][s * 32 + quad * 8];
    #pragma unroll
    for (int t = 0; t < 8; ++t) {
        f32x4 c = {0.f, 0.f, 0.f, 0.f};
        #pragma unroll
        for (int s = 0; s < 6; ++s) {
            const bf16x8 bw = *(const bf16x8*)(ws + WS_W3 + (((t * 6 + s) * 64 + lane) << 4));
            c = __builtin_amdgcn_mfma_f32_16x16x32_bf16(A3[s], bw, c, 0, 0, 0);
        }
        const float bz = ((const float*)(ws + WS_B3))[t * 16 + l15];
        #pragma unroll
        for (int r = 0; r < 4; ++r)
            out[(size_t)(p0 + quad * 4 + r) * COUT + t * 16 + l15] = lrelu(c[r] + bz);
    }
}

extern "C" void kernel_launch(void* const* d_in, const int* in_sizes, int n_in,
                              void* d_out, int out_size, void* d_ws, size_t ws_size,
                              hipStream_t stream)
{
    fp feature = (fp)d_in[1];
    fp raw     = (fp)d_in[2];
    const int* nidx = (const int*)d_in[3];
    fp W_nb = (fp)d_in[4],  b_nb = (fp)d_in[5],  g_nb = (fp)d_in[6];
    fp be_nb = (fp)d_in[7], m_nb = (fp)d_in[8],  v_nb = (fp)d_in[9];
    fp W_attn = (fp)d_in[10];
    fp W_out = (fp)d_in[11], b_out = (fp)d_in[12], g_out = (fp)d_in[13];
    fp be_out = (fp)d_in[14], m_out = (fp)d_in[15], v_out = (fp)d_in[16];
    fp W_sc = (fp)d_in[17], b_sc = (fp)d_in[18], g_sc = (fp)d_in[19];
    fp be_sc = (fp)d_in[20], m_sc = (fp)d_in[21], v_sc = (fp)d_in[22];

    hipLaunchKernelGGL(lfa_prep, dim3(22), dim3(256), 0, stream,
                       W_nb, b_nb, g_nb, be_nb, m_nb, v_nb,
                       W_attn,
                       W_out, b_out, g_out, be_out, m_out, v_out,
                       W_sc, b_sc, g_sc, be_sc, m_sc, v_sc,
                       (unsigned char*)d_ws);

    const size_t need = (size_t)WS_FEA + (size_t)NPTS * CIN * 2;
    if (ws_size >= need) {
        hipLaunchKernelGGL(lfa_prep_fea, dim3(4096), dim3(256), 0, stream,
                           feature, (unsigned char*)d_ws);
        hipLaunchKernelGGL(lfa_main_bf16, dim3(8192), dim3(64), 0, stream,
                           raw, nidx, (const unsigned char*)d_ws, (float*)d_out);
    } else {
        hipLaunchKernelGGL(lfa_main_f32, dim3(2048), dim3(256), 0, stream,
                           feature, raw, nidx,
                           (const unsigned char*)d_ws, (float*)d_out);
    }
}

// Round 10
// 456.453 us; speedup vs baseline: 1.0942x; 1.0019x over previous
//
#include <hip/hip_runtime.h>

// LocalFeatureAggregation — round 13: fix r12's FIFO hazard (stage at n0==7).
//  * r12 post-mortem: staging issued at n0==3 made the 8 random gathers OLDER
//    than n0=4..7's WB loads -> FIFO vmcnt forced a full gather drain (~600cy)
//    before the n0=4 MFMA, every iteration. MfmaUtil 14.2->11.3, 247->311us.
//  * Fix: issue staged gathers at n0==7 AFTER the last WB loads. Nothing
//    younger is consumed after them this iteration; next iteration's raw wait
//    drains them with a ~350cy head start (cost ~ raw wait alone). Explicit
//    vmcnt(0) before A-frag reads unchanged (global_load_lds->ds_read dep).
//  * Everything else byte-identical to r12 (verified: swizzle correct, bank
//    conflicts 2.29M->197K, VGPR 96, no spill).
//  * Gates: VGPR <=128; WRITE ~65.5MB; FETCH ~146MB.
// Requires ws_size >= 16864256 for the fast path (>= 86784 for fallback).

#define KNB   16
#define CR    10
#define CIN   64
#define CCAT  128
#define COUT  128
#define NPTS  131072
#define EPS   1e-5f
#define LOG2E 1.4426950408889634f

// d_ws layout (bytes)
#define WS_WB   0        // W_attn B-frags (pre-scaled by log2e): 2048 * 16 B = 32768
#define WS_W3   32768    // [W_out;W_sc] BN-folded B-frags: 3072 * 16 B = 49152
#define WS_WNB  81920    // W_nb BN-folded B-frags (K padded to 32): 256 * 16 B = 4096
#define WS_B3   86016    // bias3[128] fp32
#define WS_BNB  86528    // binb[64] fp32   -> 86784
#define WS_FEA  87040    // bf16 feature table [NPTS][CIN]: 16777216 B -> total 16864256

typedef const float* fp;
typedef short bf16x8 __attribute__((ext_vector_type(8)));
typedef float f32x4  __attribute__((ext_vector_type(4)));
typedef __bf16 bf16x2 __attribute__((ext_vector_type(2)));

__device__ __forceinline__ unsigned short f2bf(float x) {
    return __builtin_bit_cast(unsigned short, (__bf16)x);     // HW RNE cvt
}
__device__ __forceinline__ unsigned int pack2(float a, float b) {
    bf16x2 v; v.x = (__bf16)a; v.y = (__bf16)b;               // v_cvt_pk_bf16_f32
    return __builtin_bit_cast(unsigned int, v);
}
__device__ __forceinline__ float bf2f(unsigned short h) {
    return __uint_as_float(((unsigned int)h) << 16);
}
__device__ __forceinline__ float lrelu(float x) { return fmaxf(x, 0.2f * x); }

// swizzled access into a [16][64]-bf16 half-matrix (16B-chunk XOR row&7).
__device__ __forceinline__ unsigned short* swzp(unsigned short (*h)[64], int row, int c) {
    const int cg  = c >> 3;                                   // chunk 0..7
    const int off = row * 128 + (((cg ^ (row & 7)) << 4) | ((c & 7) << 1));
    return (unsigned short*)((unsigned char*)h + off);
}
__device__ __forceinline__ const unsigned short* swzc(const unsigned short (*h)[64], int row, int c) {
    const int cg  = c >> 3;
    const int off = row * 128 + (((cg ^ (row & 7)) << 4) | ((c & 7) << 1));
    return (const unsigned short*)((const unsigned char*)h + off);
}

// ---------------------------------------------------------------------------
// Prep: build all weight-fragment tables in d_ws.
// ---------------------------------------------------------------------------
__global__ __launch_bounds__(256) void lfa_prep(
    fp W_nb, fp b_nb, fp g_nb, fp be_nb, fp m_nb, fp v_nb,
    fp W_attn,
    fp W_out, fp b_out, fp g_out, fp be_out, fp m_out, fp v_out,
    fp W_sc,  fp b_sc,  fp g_sc,  fp be_sc,  fp m_sc,  fp v_sc,
    unsigned char* __restrict__ ws)
{
    const int t = blockIdx.x * 256 + threadIdx.x;
    if (t < 2048) {                                   // W_attn frags (x log2e)
        const int n0 = t >> 8, s = (t >> 6) & 3, ln = t & 63;
        const int n = (n0 << 4) + (ln & 15);
        unsigned int v[4];
        #pragma unroll
        for (int jj = 0; jj < 4; ++jj) {
            const int k = (s << 5) + ((ln >> 4) << 3) + jj * 2;
            v[jj] = pack2(W_attn[k * CCAT + n] * LOG2E,
                          W_attn[(k + 1) * CCAT + n] * LOG2E);
        }
        *(uint4*)(ws + WS_WB + t * 16) = make_uint4(v[0], v[1], v[2], v[3]);
    } else if (t < 5120) {                            // [W_out;W_sc] BN-folded frags
        const int e = t - 2048;
        const int t8 = e / 384, rem = e % 384, s = rem >> 6, ln = rem & 63;
        const int d = (t8 << 4) + (ln & 15);
        const float so = g_out[d] * rsqrtf(v_out[d] + EPS);
        const float ss = g_sc[d]  * rsqrtf(v_sc[d]  + EPS);
        unsigned int v[4];
        #pragma unroll
        for (int jj = 0; jj < 4; ++jj) {
            float a[2];
            #pragma unroll
            for (int h = 0; h < 2; ++h) {
                const int k = (s << 5) + ((ln >> 4) << 3) + jj * 2 + h;   // 0..191
                a[h] = (k < CCAT) ? W_out[k * COUT + d] * so
                                  : W_sc[(k - CCAT) * COUT + d] * ss;
            }
            v[jj] = pack2(a[0], a[1]);
        }
        *(uint4*)(ws + WS_W3 + e * 16) = make_uint4(v[0], v[1], v[2], v[3]);
    } else if (t < 5376) {                            // W_nb BN-prescaled frags
        const int e = t - 5120;
        const int n0 = e >> 6, ln = e & 63;
        const int n = (n0 << 4) + (ln & 15);
        const float sn = g_nb[n] * rsqrtf(v_nb[n] + EPS);
        unsigned int v[4];
        #pragma unroll
        for (int jj = 0; jj < 4; ++jj) {
            float a[2];
            #pragma unroll
            for (int h = 0; h < 2; ++h) {
                const int k = ((ln >> 4) << 3) + jj * 2 + h;
                a[h] = (k < CR) ? W_nb[k * 64 + n] * sn : 0.f;
            }
            v[jj] = pack2(a[0], a[1]);
        }
        *(uint4*)(ws + WS_WNB + e * 16) = make_uint4(v[0], v[1], v[2], v[3]);
    } else if (t < 5504) {                            // bias3
        const int d = t - 5376;
        const float so = g_out[d] * rsqrtf(v_out[d] + EPS);
        const float ss = g_sc[d]  * rsqrtf(v_sc[d]  + EPS);
        ((float*)(ws + WS_B3))[d] =
              (b_out[d] - m_out[d]) * so + be_out[d]
            + (b_sc[d]  - m_sc[d])  * ss + be_sc[d];
    } else if (t < 5568) {                            // nb bias
        const int d = t - 5504;
        const float sn = g_nb[d] * rsqrtf(v_nb[d] + EPS);
        ((float*)(ws + WS_BNB))[d] = (b_nb[d] - m_nb[d]) * sn + be_nb[d];
    }
}

// ---------------------------------------------------------------------------
// Prep 2: bf16 feature table [NPTS][CIN] into ws+WS_FEA (8 ch per thread).
// ---------------------------------------------------------------------------
__global__ __launch_bounds__(256) void lfa_prep_fea(
    fp feature, unsigned char* __restrict__ ws)
{
    const int t = blockIdx.x * 256 + threadIdx.x;
    const size_t idx = (size_t)t * 8;
    if (idx < (size_t)NPTS * CIN) {
        const float4 f0 = *(const float4*)&feature[idx];
        const float4 f1 = *(const float4*)&feature[idx + 4];
        uint4 o;
        o.x = pack2(f0.x, f0.y); o.y = pack2(f0.z, f0.w);
        o.z = pack2(f1.x, f1.y); o.w = pack2(f1.z, f1.w);
        *(uint4*)(ws + WS_FEA + idx * 2) = o;
    }
}

// ---------------------------------------------------------------------------
// Main (fast path): 1-wave blocks, r9 point-paired loop + LDS-staged gathers
// issued at n0==7 (younger than all WB loads -> no FIFO drain in phase 2).
// 8192 blocks x 64 thr, 16 pts/block. LDS = 18688 B. VGPR target <=128.
// ---------------------------------------------------------------------------
__global__ __launch_bounds__(64, 2) void lfa_main_bf16(
    fp raw, const int* __restrict__ nidx,
    const unsigned char* __restrict__ ws, float* __restrict__ out)
{
    __shared__ __align__(16) unsigned short feaG[2][2][16][64];  // 8192 B (dbuf x pt)
    __shared__ __align__(16) unsigned short feaN[2][16][64];     // 4096 B (pt)
    __shared__ __align__(16) unsigned short pooledA[16][200];    // 6400 B

    const int lane = threadIdx.x;              // 0..63
    const int quad = lane >> 4;
    const int l15  = lane & 15;
    const int p0   = blockIdx.x * 16;          // block's 16 points
    const int b    = p0 >> 16;                 // batch (16-pt range never straddles)

    const unsigned short* feaT = (const unsigned short*)(ws + WS_FEA);
    const unsigned char*  wbp  = ws + WS_WB + ((size_t)lane << 4);

    // lane's pre-swizzled source chunk offset (rule #21 both-sides pattern)
    const int srcswz = ((lane & 7) ^ (lane >> 3)) << 4;
    const int rowsh  = lane >> 3;              // dest row within 8-row group

    // ---- hoisted: center rows for ALL 16 points -> pooledA[:,128..191] ----
    #pragma unroll
    for (int j = 0; j < 4; ++j) {
        const int e   = j * 64 + lane;         // 0..255
        const int row = e >> 4, c4 = (e & 15) * 4;
        const uint2 cf = *(const uint2*)&feaT[(size_t)(p0 + row) * CIN + c4];
        *(uint2*)&pooledA[row][CCAT + c4] = cf;
    }

    float binb[4];
    #pragma unroll
    for (int j = 0; j < 4; ++j)
        binb[j] = ((const float*)(ws + WS_BNB))[j * 16 + l15];

    // ---- prologue: idx(0) + stage it=0 gathers into feaG[0] ----
    int idxv = 0;
    if (lane < 32) idxv = nidx[p0 * KNB + lane];
    #pragma unroll
    for (int pt = 0; pt < 2; ++pt)
        #pragma unroll
        for (int i = 0; i < 2; ++i) {
            const int ni = __shfl(idxv, pt * 16 + i * 8 + rowsh, 64);
            const unsigned char* src = (const unsigned char*)feaT
                + (((size_t)((b << 16) + ni)) << 7) + srcswz;
            __builtin_amdgcn_global_load_lds(
                (__attribute__((address_space(1))) const void*)src,
                (__attribute__((address_space(3))) void*)
                    ((unsigned char*)&feaG[0][pt][0][0] + i * 1024),
                16, 0, 0);
        }

    int cur = 0;
    #pragma unroll 1
    for (int it = 0; it < 8; ++it) {
        const int  pp0  = p0 + it * 2;
        const bool more = (it < 7);

        // ---- idx for it+1 (consumed at n0==7 for staging) ----
        int idxn = 0;
        if (more && lane < 32) idxn = nidx[(pp0 + 2) * KNB + lane];

        // ---- raw JIT loads + anb pack (r9 pattern, short-lived regs) ----
        bf16x8 anb[2];
        #pragma unroll
        for (int pt = 0; pt < 2; ++pt) {
            bf16x8 a = {0, 0, 0, 0, 0, 0, 0, 0};
            const float* rp = raw + (size_t)(pp0 + pt) * (KNB * CR) + l15 * CR;
            if (quad == 0) {
                const float2 r0 = *(const float2*)(rp + 0);
                const float2 r1 = *(const float2*)(rp + 2);
                const float2 r2 = *(const float2*)(rp + 4);
                const float2 r3 = *(const float2*)(rp + 6);
                a[0] = (short)f2bf(r0.x); a[1] = (short)f2bf(r0.y);
                a[2] = (short)f2bf(r1.x); a[3] = (short)f2bf(r1.y);
                a[4] = (short)f2bf(r2.x); a[5] = (short)f2bf(r2.y);
                a[6] = (short)f2bf(r3.x); a[7] = (short)f2bf(r3.y);
            } else if (quad == 1) {
                const float2 r4 = *(const float2*)(rp + 8);
                a[0] = (short)f2bf(r4.x); a[1] = (short)f2bf(r4.y);
            }
            anb[pt] = a;
        }

        // ---- nb-MLP: per-tile WNB frag (L1-hit) -> two MFMAs -> feaN (swz) ----
        float nbC[2][4][4];
        #pragma unroll
        for (int n0 = 0; n0 < 4; ++n0) {
            const bf16x8 bw = *(const bf16x8*)(ws + WS_WNB + ((n0 * 64 + lane) << 4));
            f32x4 c0 = {0.f, 0.f, 0.f, 0.f};
            f32x4 c1 = {0.f, 0.f, 0.f, 0.f};
            c0 = __builtin_amdgcn_mfma_f32_16x16x32_bf16(anb[0], bw, c0, 0, 0, 0);
            c1 = __builtin_amdgcn_mfma_f32_16x16x32_bf16(anb[1], bw, c1, 0, 0, 0);
            #pragma unroll
            for (int r = 0; r < 4; ++r) {
                const float x0 = lrelu(c0[r] + binb[n0]);
                const float x1 = lrelu(c1[r] + binb[n0]);
                nbC[0][n0][r] = x0;
                nbC[1][n0][r] = x1;
                *swzp(feaN[0], quad * 4 + r, n0 * 16 + l15) = f2bf(x0);
                *swzp(feaN[1], quad * 4 + r, n0 * 16 + l15) = f2bf(x1);
            }
        }

        // ---- staged gathers for THIS iteration are now needed ----
        asm volatile("s_waitcnt vmcnt(0)" ::: "memory");

        // ---- attn A-frags: s=0,1 from feaG[cur] (swz), s=2,3 from feaN (swz) ----
        bf16x8 A[2][4];
        #pragma unroll
        for (int pt = 0; pt < 2; ++pt) {
            A[pt][0] = *(const bf16x8*)swzc(feaG[cur][pt], l15, 0  + quad * 8);
            A[pt][1] = *(const bf16x8*)swzc(feaG[cur][pt], l15, 32 + quad * 8);
            A[pt][2] = *(const bf16x8*)swzc(feaN[pt],      l15, 0  + quad * 8);
            A[pt][3] = *(const bf16x8*)swzc(feaN[pt],      l15, 32 + quad * 8);
        }

        // ---- phase 2: 8 d-tiles, ONE wb set -> TWO independent MFMA chains ----
        #pragma unroll
        for (int n0 = 0; n0 < 8; ++n0) {
            const bf16x8 wb0 = *(const bf16x8*)(wbp + (n0 * 4 + 0) * 1024);
            const bf16x8 wb1 = *(const bf16x8*)(wbp + (n0 * 4 + 1) * 1024);
            const bf16x8 wb2 = *(const bf16x8*)(wbp + (n0 * 4 + 2) * 1024);
            const bf16x8 wb3 = *(const bf16x8*)(wbp + (n0 * 4 + 3) * 1024);
            f32x4 c0 = {0.f, 0.f, 0.f, 0.f};
            f32x4 c1 = {0.f, 0.f, 0.f, 0.f};
            c0 = __builtin_amdgcn_mfma_f32_16x16x32_bf16(A[0][0], wb0, c0, 0, 0, 0);
            c1 = __builtin_amdgcn_mfma_f32_16x16x32_bf16(A[1][0], wb0, c1, 0, 0, 0);
            c0 = __builtin_amdgcn_mfma_f32_16x16x32_bf16(A[0][1], wb1, c0, 0, 0, 0);
            c1 = __builtin_amdgcn_mfma_f32_16x16x32_bf16(A[1][1], wb1, c1, 0, 0, 0);
            c0 = __builtin_amdgcn_mfma_f32_16x16x32_bf16(A[0][2], wb2, c0, 0, 0, 0);
            c1 = __builtin_amdgcn_mfma_f32_16x16x32_bf16(A[1][2], wb2, c1, 0, 0, 0);
            c0 = __builtin_amdgcn_mfma_f32_16x16x32_bf16(A[0][3], wb3, c0, 0, 0, 0);
            c1 = __builtin_amdgcn_mfma_f32_16x16x32_bf16(A[1][3], wb3, c1, 0, 0, 0);

            // n0==7: issue it+1's staged gathers — YOUNGER than every WB load
            // of this iteration, so no phase-2 consumption FIFO-drains them.
            // Flight window: n0=7 softmax + pooled + next top idx/raw + anb +
            // nb-MLP (~700cy), drained at the next vmcnt(0).
            if (n0 == 7 && more) {
                #pragma unroll
                for (int pt = 0; pt < 2; ++pt)
                    #pragma unroll
                    for (int i = 0; i < 2; ++i) {
                        const int ni = __shfl(idxn, pt * 16 + i * 8 + rowsh, 64);
                        const unsigned char* src = (const unsigned char*)feaT
                            + (((size_t)((b << 16) + ni)) << 7) + srcswz;
                        __builtin_amdgcn_global_load_lds(
                            (__attribute__((address_space(1))) const void*)src,
                            (__attribute__((address_space(3))) void*)
                                ((unsigned char*)&feaG[cur ^ 1][pt][0][0] + i * 1024),
                            16, 0, 0);
                    }
            }

            const float e00 = __builtin_amdgcn_exp2f(c0[0]);
            const float e01 = __builtin_amdgcn_exp2f(c0[1]);
            const float e02 = __builtin_amdgcn_exp2f(c0[2]);
            const float e03 = __builtin_amdgcn_exp2f(c0[3]);
            const float e10 = __builtin_amdgcn_exp2f(c1[0]);
            const float e11 = __builtin_amdgcn_exp2f(c1[1]);
            const float e12 = __builtin_amdgcn_exp2f(c1[2]);
            const float e13 = __builtin_amdgcn_exp2f(c1[3]);
            float den0 = e00 + e01 + e02 + e03;
            float den1 = e10 + e11 + e12 + e13;
            float num0, num1;
            if (n0 < 4) {
                num0 = e00 * bf2f(*swzc(feaG[cur][0], quad * 4 + 0, n0 * 16 + l15))
                     + e01 * bf2f(*swzc(feaG[cur][0], quad * 4 + 1, n0 * 16 + l15))
                     + e02 * bf2f(*swzc(feaG[cur][0], quad * 4 + 2, n0 * 16 + l15))
                     + e03 * bf2f(*swzc(feaG[cur][0], quad * 4 + 3, n0 * 16 + l15));
                num1 = e10 * bf2f(*swzc(feaG[cur][1], quad * 4 + 0, n0 * 16 + l15))
                     + e11 * bf2f(*swzc(feaG[cur][1], quad * 4 + 1, n0 * 16 + l15))
                     + e12 * bf2f(*swzc(feaG[cur][1], quad * 4 + 2, n0 * 16 + l15))
                     + e13 * bf2f(*swzc(feaG[cur][1], quad * 4 + 3, n0 * 16 + l15));
            } else {
                num0 = e00 * nbC[0][n0 - 4][0] + e01 * nbC[0][n0 - 4][1]
                     + e02 * nbC[0][n0 - 4][2] + e03 * nbC[0][n0 - 4][3];
                num1 = e10 * nbC[1][n0 - 4][0] + e11 * nbC[1][n0 - 4][1]
                     + e12 * nbC[1][n0 - 4][2] + e13 * nbC[1][n0 - 4][3];
            }
            num0 += __shfl_xor(num0, 16, 64);
            den0 += __shfl_xor(den0, 16, 64);
            num1 += __shfl_xor(num1, 16, 64);
            den1 += __shfl_xor(den1, 16, 64);
            num0 += __shfl_xor(num0, 32, 64);
            den0 += __shfl_xor(den0, 32, 64);
            num1 += __shfl_xor(num1, 32, 64);
            den1 += __shfl_xor(den1, 32, 64);
            const float pp0v = __fdividef(num0, den0);
            const float pp1v = __fdividef(num1, den1);
            if (quad == 0) {
                pooledA[it * 2 + 0][n0 * 16 + l15] = f2bf(pp0v);
                pooledA[it * 2 + 1][n0 * 16 + l15] = f2bf(pp1v);
            }
        }

        cur ^= 1;
    }

    // ---- fused phase 3: out = lrelu([pooled|feat] @ W3hat + bias3), M=16 ----
    bf16x8 A3[6];
    #pragma unroll
    for (int s = 0; s < 6; ++s)
        A3[s] = *(const bf16x8*)&pooledA[l15][s * 32 + quad * 8];
    #pragma unroll
    for (int t = 0; t < 8; ++t) {
        f32x4 c = {0.f, 0.f, 0.f, 0.f};
        #pragma unroll
        for (int s = 0; s < 6; ++s) {
            const bf16x8 bw = *(const bf16x8*)(ws + WS_W3 + (((t * 6 + s) * 64 + lane) << 4));
            c = __builtin_amdgcn_mfma_f32_16x16x32_bf16(A3[s], bw, c, 0, 0, 0);
        }
        const float bz = ((const float*)(ws + WS_B3))[t * 16 + l15];
        #pragma unroll
        for (int r = 0; r < 4; ++r)
            out[(size_t)(p0 + quad * 4 + r) * COUT + t * 16 + l15] = lrelu(c[r] + bz);
    }
}

// ---------------------------------------------------------------------------
// Fallback main (exact r5 kernel, known 270 us): used if ws too small.
// ---------------------------------------------------------------------------
__global__ __launch_bounds__(256, 2) void lfa_main_f32(
    fp feature, fp raw, const int* __restrict__ nidx,
    const unsigned char* __restrict__ ws, float* __restrict__ out)
{
    __shared__ __align__(16) unsigned short feaA[4][16][136];
    __shared__ __align__(16) unsigned short pooledA[4][16][200];

    const int tid  = threadIdx.x;
    const int w    = tid >> 6;
    const int lane = tid & 63;
    const int quad = lane >> 4;
    const int l15  = lane & 15;
    const int p0   = (blockIdx.x * 4 + w) * 16;
    const int b    = p0 >> 16;

    bf16x8 WB[8][4];
    #pragma unroll
    for (int n0 = 0; n0 < 8; ++n0)
        #pragma unroll
        for (int s = 0; s < 4; ++s)
            WB[n0][s] = *(const bf16x8*)(ws + WS_WB + (((n0 * 4 + s) * 64 + lane) << 4));

    float binb[4];
    #pragma unroll
    for (int j = 0; j < 4; ++j)
        binb[j] = ((const float*)(ws + WS_BNB))[j * 16 + l15];

    #pragma unroll 1
    for (int it = 0; it < 8; ++it) {
        const int pp0 = p0 + it * 2;

        int idxv = 0;
        if (lane < 32) idxv = nidx[pp0 * KNB + lane];

        if (lane < 32) {
            const int pt = lane >> 4, c4 = l15 * 4;
            const float4 cf = *(const float4*)&feature[(size_t)(pp0 + pt) * CIN + c4];
            uint2 pk; pk.x = pack2(cf.x, cf.y); pk.y = pack2(cf.z, cf.w);
            *(uint2*)&pooledA[w][it * 2 + pt][CCAT + c4] = pk;
        }

        #pragma unroll
        for (int pt = 0; pt < 2; ++pt) {
            const int p = pp0 + pt;

            float4 gv[4];
            #pragma unroll
            for (int i = 0; i < 4; ++i) {
                const int ni = __shfl(idxv, pt * 16 + i * 4 + quad, 64);
                gv[i] = *(const float4*)&feature[(size_t)((b << 16) + ni) * CIN + l15 * 4];
            }

            bf16x8 anb = {0, 0, 0, 0, 0, 0, 0, 0};
            {
                const float* rp = raw + (size_t)p * (KNB * CR) + l15 * CR;
                if (quad == 0) {
                    const float2 r0 = *(const float2*)(rp + 0);
                    const float2 r1 = *(const float2*)(rp + 2);
                    const float2 r2 = *(const float2*)(rp + 4);
                    const float2 r3 = *(const float2*)(rp + 6);
                    anb[0] = (short)f2bf(r0.x); anb[1] = (short)f2bf(r0.y);
                    anb[2] = (short)f2bf(r1.x); anb[3] = (short)f2bf(r1.y);
                    anb[4] = (short)f2bf(r2.x); anb[5] = (short)f2bf(r2.y);
                    anb[6] = (short)f2bf(r3.x); anb[7] = (short)f2bf(r3.y);
                } else if (quad == 1) {
                    const float2 r4 = *(const float2*)(rp + 8);
                    anb[0] = (short)f2bf(r4.x); anb[1] = (short)f2bf(r4.y);
                }
            }

            float nbC[4][4];
            #pragma unroll
            for (int n0 = 0; n0 < 4; ++n0) {
                const bf16x8 bw = *(const bf16x8*)(ws + WS_WNB + ((n0 * 64 + lane) << 4));
                f32x4 c = {0.f, 0.f, 0.f, 0.f};
                c = __builtin_amdgcn_mfma_f32_16x16x32_bf16(anb, bw, c, 0, 0, 0);
                #pragma unroll
                for (int r = 0; r < 4; ++r) {
                    const float x = lrelu(c[r] + binb[n0]);
                    nbC[n0][r] = x;
                    feaA[w][quad * 4 + r][64 + n0 * 16 + l15] = f2bf(x);
                }
            }

            #pragma unroll
            for (int i = 0; i < 4; ++i) {
                uint2 pk; pk.x = pack2(gv[i].x, gv[i].y); pk.y = pack2(gv[i].z, gv[i].w);
                *(uint2*)&feaA[w][i * 4 + quad][l15 * 4] = pk;
            }

            bf16x8 A[4];
            #pragma unroll
            for (int s = 0; s < 4; ++s)
                A[s] = *(const bf16x8*)&feaA[w][l15][s * 32 + quad * 8];

            #pragma unroll
            for (int n0 = 0; n0 < 8; ++n0) {
                f32x4 c = {0.f, 0.f, 0.f, 0.f};
                #pragma unroll
                for (int s = 0; s < 4; ++s)
                    c = __builtin_amdgcn_mfma_f32_16x16x32_bf16(A[s], WB[n0][s], c, 0, 0, 0);
                const float e0 = __builtin_amdgcn_exp2f(c[0]);
                const float e1 = __builtin_amdgcn_exp2f(c[1]);
                const float e2 = __builtin_amdgcn_exp2f(c[2]);
                const float e3 = __builtin_amdgcn_exp2f(c[3]);
                float den = e0 + e1 + e2 + e3;
                float num;
                if (n0 < 4) {
                    num = e0 * bf2f(feaA[w][quad * 4 + 0][n0 * 16 + l15])
                        + e1 * bf2f(feaA[w][quad * 4 + 1][n0 * 16 + l15])
                        + e2 * bf2f(feaA[w][quad * 4 + 2][n0 * 16 + l15])
                        + e3 * bf2f(feaA[w][quad * 4 + 3][n0 * 16 + l15]);
                } else {
                    num = e0 * nbC[n0 - 4][0] + e1 * nbC[n0 - 4][1]
                        + e2 * nbC[n0 - 4][2] + e3 * nbC[n0 - 4][3];
                }
                num += __shfl_xor(num, 16, 64);
                den += __shfl_xor(den, 16, 64);
                num += __shfl_xor(num, 32, 64);
                den += __shfl_xor(den, 32, 64);
                const float pp = __fdividef(num, den);
                if (quad == 0)
                    pooledA[w][it * 2 + pt][n0 * 16 + l15] = f2bf(pp);
            }
        }
    }

    bf16x8 A3[6];
    #pragma unroll
    for (int s = 0; s < 6; ++s)
        A3[s] = *(const bf16x8*)&pooledA[w][l15][s * 32 + quad * 8];
    #pragma unroll
    for (int t = 0; t < 8; ++t) {
        f32x4 c = {0.f, 0.f, 0.f, 0.f};
        #pragma unroll
        for (int s = 0; s < 6; ++s) {
            const bf16x8 bw = *(const bf16x8*)(ws + WS_W3 + (((t * 6 + s) * 64 + lane) << 4));
            c = __builtin_amdgcn_mfma_f32_16x16x32_bf16(A3[s], bw, c, 0, 0, 0);
        }
        const float bz = ((const float*)(ws + WS_B3))[t * 16 + l15];
        #pragma unroll
        for (int r = 0; r < 4; ++r)
            out[(size_t)(p0 + quad * 4 + r) * COUT + t * 16 + l15] = lrelu(c[r] + bz);
    }
}

extern "C" void kernel_launch(void* const* d_in, const int* in_sizes, int n_in,
                              void* d_out, int out_size, void* d_ws, size_t ws_size,
                              hipStream_t stream)
{
    fp feature = (fp)d_in[1];
    fp raw     = (fp)d_in[2];
    const int* nidx = (const int*)d_in[3];
    fp W_nb = (fp)d_in[4],  b_nb = (fp)d_in[5],  g_nb = (fp)d_in[6];
    fp be_nb = (fp)d_in[7], m_nb = (fp)d_in[8],  v_nb = (fp)d_in[9];
    fp W_attn = (fp)d_in[10];
    fp W_out = (fp)d_in[11], b_out = (fp)d_in[12], g_out = (fp)d_in[13];
    fp be_out = (fp)d_in[14], m_out = (fp)d_in[15], v_out = (fp)d_in[16];
    fp W_sc = (fp)d_in[17], b_sc = (fp)d_in[18], g_sc = (fp)d_in[19];
    fp be_sc = (fp)d_in[20], m_sc = (fp)d_in[21], v_sc = (fp)d_in[22];

    hipLaunchKernelGGL(lfa_prep, dim3(22), dim3(256), 0, stream,
                       W_nb, b_nb, g_nb, be_nb, m_nb, v_nb,
                       W_attn,
                       W_out, b_out, g_out, be_out, m_out, v_out,
                       W_sc, b_sc, g_sc, be_sc, m_sc, v_sc,
                       (unsigned char*)d_ws);

    const size_t need = (size_t)WS_FEA + (size_t)NPTS * CIN * 2;
    if (ws_size >= need) {
        hipLaunchKernelGGL(lfa_prep_fea, dim3(4096), dim3(256), 0, stream,
                           feature, (unsigned char*)d_ws);
        hipLaunchKernelGGL(lfa_main_bf16, dim3(8192), dim3(64), 0, stream,
                           raw, nidx, (const unsigned char*)d_ws, (float*)d_out);
    } else {
        hipLaunchKernelGGL(lfa_main_f32, dim3(2048), dim3(256), 0, stream,
                           feature, raw, nidx,
                           (const unsigned char*)d_ws, (float*)d_out);
    }
}

// Round 11
// 397.562 us; speedup vs baseline: 1.2563x; 1.1481x over previous
//
#include <hip/hip_runtime.h>

// LocalFeatureAggregation — round 14: r9 base + serial-chain cuts (no staging).
//  * r12/r13 verdict: LDS-staged gathers (global_load_lds + swizzle) lose to
//    r9's register gathers (293 vs 247us) — vmcnt(0) full-drain + swizzle VALU
//    overhead > hidden latency. Staging arc abandoned; r9 is the base.
//  * Change 1: delete idx->shfl chain. Lane (quad,l15) gathers rows quad*4+i;
//    its 4 indices are contiguous -> ONE aligned int4 load per pt per lane
//    (L1 broadcast), no ds_bpermute, no wave-wide idx sync. Row permutation
//    only changes which lane writes which feaA row; content identical.
//  * Change 2: s_setprio(1) around phase-2 MFMA cluster (T5/m191 regime:
//    1-wave blocks, independent phases, ~2 waves/SIMD).
//  * Keep: hoisted center rows, bf16 feature table, point-paired ILP loop,
//    per-tile streamed WB frags, (64,2) bounds, VGPR<=128 law.
//  * Gates: VGPR <=128; WRITE ~65.5MB; FETCH ~146MB.
// Requires ws_size >= 16864256 for the fast path (>= 86784 for fallback).

#define KNB   16
#define CR    10
#define CIN   64
#define CCAT  128
#define COUT  128
#define NPTS  131072
#define EPS   1e-5f
#define LOG2E 1.4426950408889634f

// d_ws layout (bytes)
#define WS_WB   0        // W_attn B-frags (pre-scaled by log2e): 2048 * 16 B = 32768
#define WS_W3   32768    // [W_out;W_sc] BN-folded B-frags: 3072 * 16 B = 49152
#define WS_WNB  81920    // W_nb BN-folded B-frags (K padded to 32): 256 * 16 B = 4096
#define WS_B3   86016    // bias3[128] fp32
#define WS_BNB  86528    // binb[64] fp32   -> 86784
#define WS_FEA  87040    // bf16 feature table [NPTS][CIN]: 16777216 B -> total 16864256

typedef const float* fp;
typedef short bf16x8 __attribute__((ext_vector_type(8)));
typedef float f32x4  __attribute__((ext_vector_type(4)));
typedef __bf16 bf16x2 __attribute__((ext_vector_type(2)));

__device__ __forceinline__ unsigned short f2bf(float x) {
    return __builtin_bit_cast(unsigned short, (__bf16)x);     // HW RNE cvt
}
__device__ __forceinline__ unsigned int pack2(float a, float b) {
    bf16x2 v; v.x = (__bf16)a; v.y = (__bf16)b;               // v_cvt_pk_bf16_f32
    return __builtin_bit_cast(unsigned int, v);
}
__device__ __forceinline__ float bf2f(unsigned short h) {
    return __uint_as_float(((unsigned int)h) << 16);
}
__device__ __forceinline__ float lrelu(float x) { return fmaxf(x, 0.2f * x); }

// ---------------------------------------------------------------------------
// Prep: build all weight-fragment tables in d_ws.
// ---------------------------------------------------------------------------
__global__ __launch_bounds__(256) void lfa_prep(
    fp W_nb, fp b_nb, fp g_nb, fp be_nb, fp m_nb, fp v_nb,
    fp W_attn,
    fp W_out, fp b_out, fp g_out, fp be_out, fp m_out, fp v_out,
    fp W_sc,  fp b_sc,  fp g_sc,  fp be_sc,  fp m_sc,  fp v_sc,
    unsigned char* __restrict__ ws)
{
    const int t = blockIdx.x * 256 + threadIdx.x;
    if (t < 2048) {                                   // W_attn frags (x log2e)
        const int n0 = t >> 8, s = (t >> 6) & 3, ln = t & 63;
        const int n = (n0 << 4) + (ln & 15);
        unsigned int v[4];
        #pragma unroll
        for (int jj = 0; jj < 4; ++jj) {
            const int k = (s << 5) + ((ln >> 4) << 3) + jj * 2;
            v[jj] = pack2(W_attn[k * CCAT + n] * LOG2E,
                          W_attn[(k + 1) * CCAT + n] * LOG2E);
        }
        *(uint4*)(ws + WS_WB + t * 16) = make_uint4(v[0], v[1], v[2], v[3]);
    } else if (t < 5120) {                            // [W_out;W_sc] BN-folded frags
        const int e = t - 2048;
        const int t8 = e / 384, rem = e % 384, s = rem >> 6, ln = rem & 63;
        const int d = (t8 << 4) + (ln & 15);
        const float so = g_out[d] * rsqrtf(v_out[d] + EPS);
        const float ss = g_sc[d]  * rsqrtf(v_sc[d]  + EPS);
        unsigned int v[4];
        #pragma unroll
        for (int jj = 0; jj < 4; ++jj) {
            float a[2];
            #pragma unroll
            for (int h = 0; h < 2; ++h) {
                const int k = (s << 5) + ((ln >> 4) << 3) + jj * 2 + h;   // 0..191
                a[h] = (k < CCAT) ? W_out[k * COUT + d] * so
                                  : W_sc[(k - CCAT) * COUT + d] * ss;
            }
            v[jj] = pack2(a[0], a[1]);
        }
        *(uint4*)(ws + WS_W3 + e * 16) = make_uint4(v[0], v[1], v[2], v[3]);
    } else if (t < 5376) {                            // W_nb BN-prescaled frags
        const int e = t - 5120;
        const int n0 = e >> 6, ln = e & 63;
        const int n = (n0 << 4) + (ln & 15);
        const float sn = g_nb[n] * rsqrtf(v_nb[n] + EPS);
        unsigned int v[4];
        #pragma unroll
        for (int jj = 0; jj < 4; ++jj) {
            float a[2];
            #pragma unroll
            for (int h = 0; h < 2; ++h) {
                const int k = ((ln >> 4) << 3) + jj * 2 + h;
                a[h] = (k < CR) ? W_nb[k * 64 + n] * sn : 0.f;
            }
            v[jj] = pack2(a[0], a[1]);
        }
        *(uint4*)(ws + WS_WNB + e * 16) = make_uint4(v[0], v[1], v[2], v[3]);
    } else if (t < 5504) {                            // bias3
        const int d = t - 5376;
        const float so = g_out[d] * rsqrtf(v_out[d] + EPS);
        const float ss = g_sc[d]  * rsqrtf(v_sc[d]  + EPS);
        ((float*)(ws + WS_B3))[d] =
              (b_out[d] - m_out[d]) * so + be_out[d]
            + (b_sc[d]  - m_sc[d])  * ss + be_sc[d];
    } else if (t < 5568) {                            // nb bias
        const int d = t - 5504;
        const float sn = g_nb[d] * rsqrtf(v_nb[d] + EPS);
        ((float*)(ws + WS_BNB))[d] = (b_nb[d] - m_nb[d]) * sn + be_nb[d];
    }
}

// ---------------------------------------------------------------------------
// Prep 2: bf16 feature table [NPTS][CIN] into ws+WS_FEA (8 ch per thread).
// ---------------------------------------------------------------------------
__global__ __launch_bounds__(256) void lfa_prep_fea(
    fp feature, unsigned char* __restrict__ ws)
{
    const int t = blockIdx.x * 256 + threadIdx.x;
    const size_t idx = (size_t)t * 8;
    if (idx < (size_t)NPTS * CIN) {
        const float4 f0 = *(const float4*)&feature[idx];
        const float4 f1 = *(const float4*)&feature[idx + 4];
        uint4 o;
        o.x = pack2(f0.x, f0.y); o.y = pack2(f0.z, f0.w);
        o.z = pack2(f1.x, f1.y); o.w = pack2(f1.z, f1.w);
        *(uint4*)(ws + WS_FEA + idx * 2) = o;
    }
}

// ---------------------------------------------------------------------------
// Main (fast path): ONE WAVE PER BLOCK, point-paired inner loop, direct
// per-lane int4 index loads (no shfl), setprio around MFMA cluster.
// 8192 blocks x 64 thr, 16 pts/block. LDS = 15104 B. VGPR target <=128.
// ---------------------------------------------------------------------------
__global__ __launch_bounds__(64, 2) void lfa_main_bf16(
    fp raw, const int* __restrict__ nidx,
    const unsigned char* __restrict__ ws, float* __restrict__ out)
{
    __shared__ __align__(16) unsigned short feaA[2][16][136];   // 8704 B
    __shared__ __align__(16) unsigned short pooledA[16][200];   // 6400 B

    const int lane = threadIdx.x;              // 0..63
    const int quad = lane >> 4;
    const int l15  = lane & 15;
    const int p0   = blockIdx.x * 16;          // block's 16 points
    const int b    = p0 >> 16;                 // batch (16-pt range never straddles)

    const unsigned short* feaT = (const unsigned short*)(ws + WS_FEA);
    const unsigned char*  wbp  = ws + WS_WB + ((size_t)lane << 4);

    // ---- hoisted: center rows for ALL 16 points -> pooledA[:,128..191] ----
    #pragma unroll
    for (int j = 0; j < 4; ++j) {
        const int e   = j * 64 + lane;         // 0..255
        const int row = e >> 4, c4 = (e & 15) * 4;
        const uint2 cf = *(const uint2*)&feaT[(size_t)(p0 + row) * CIN + c4];
        *(uint2*)&pooledA[row][CCAT + c4] = cf;
    }

    float binb[4];
    #pragma unroll
    for (int j = 0; j < 4; ++j)
        binb[j] = ((const float*)(ws + WS_BNB))[j * 16 + l15];

    #pragma unroll 1
    for (int it = 0; it < 8; ++it) {
        const int pp0 = p0 + it * 2;

        // ---- phase 1a: gathers for BOTH points; indices via direct per-lane
        //      int4 load (contiguous, L1-broadcast) — NO shfl chain ----
        uint2 gv[2][4];
        #pragma unroll
        for (int pt = 0; pt < 2; ++pt) {
            const int4 ni4 = *(const int4*)&nidx[(size_t)(pp0 + pt) * KNB + quad * 4];
            const int n0i = ni4.x, n1i = ni4.y, n2i = ni4.z, n3i = ni4.w;
            gv[pt][0] = *(const uint2*)&feaT[(size_t)((b << 16) + n0i) * CIN + l15 * 4];
            gv[pt][1] = *(const uint2*)&feaT[(size_t)((b << 16) + n1i) * CIN + l15 * 4];
            gv[pt][2] = *(const uint2*)&feaT[(size_t)((b << 16) + n2i) * CIN + l15 * 4];
            gv[pt][3] = *(const uint2*)&feaT[(size_t)((b << 16) + n3i) * CIN + l15 * 4];
        }

        // ---- phase 1b: raw loads + bf16 pack for BOTH points ----
        bf16x8 anb[2];
        #pragma unroll
        for (int pt = 0; pt < 2; ++pt) {
            bf16x8 a = {0, 0, 0, 0, 0, 0, 0, 0};
            const float* rp = raw + (size_t)(pp0 + pt) * (KNB * CR) + l15 * CR;
            if (quad == 0) {
                const float2 r0 = *(const float2*)(rp + 0);
                const float2 r1 = *(const float2*)(rp + 2);
                const float2 r2 = *(const float2*)(rp + 4);
                const float2 r3 = *(const float2*)(rp + 6);
                a[0] = (short)f2bf(r0.x); a[1] = (short)f2bf(r0.y);
                a[2] = (short)f2bf(r1.x); a[3] = (short)f2bf(r1.y);
                a[4] = (short)f2bf(r2.x); a[5] = (short)f2bf(r2.y);
                a[6] = (short)f2bf(r3.x); a[7] = (short)f2bf(r3.y);
            } else if (quad == 1) {
                const float2 r4 = *(const float2*)(rp + 8);
                a[0] = (short)f2bf(r4.x); a[1] = (short)f2bf(r4.y);
            }
            anb[pt] = a;
        }

        // ---- phase 1c: nb-MLP, shared bw load -> two MFMAs ----
        float nbC[2][4][4];
        #pragma unroll
        for (int n0 = 0; n0 < 4; ++n0) {
            const bf16x8 bw = *(const bf16x8*)(ws + WS_WNB + ((n0 * 64 + lane) << 4));
            f32x4 c0 = {0.f, 0.f, 0.f, 0.f};
            f32x4 c1 = {0.f, 0.f, 0.f, 0.f};
            c0 = __builtin_amdgcn_mfma_f32_16x16x32_bf16(anb[0], bw, c0, 0, 0, 0);
            c1 = __builtin_amdgcn_mfma_f32_16x16x32_bf16(anb[1], bw, c1, 0, 0, 0);
            #pragma unroll
            for (int r = 0; r < 4; ++r) {
                const float x0 = lrelu(c0[r] + binb[n0]);
                const float x1 = lrelu(c1[r] + binb[n0]);
                nbC[0][n0][r] = x0;
                nbC[1][n0][r] = x1;
                feaA[0][quad * 4 + r][64 + n0 * 16 + l15] = f2bf(x0);
                feaA[1][quad * 4 + r][64 + n0 * 16 + l15] = f2bf(x1);
            }
        }

        // ---- phase 1d: gather writes (lane owns rows quad*4+i) ----
        #pragma unroll
        for (int pt = 0; pt < 2; ++pt)
            #pragma unroll
            for (int i = 0; i < 4; ++i)
                *(uint2*)&feaA[pt][quad * 4 + i][l15 * 4] = gv[pt][i];

        // ---- attn A-frags for both pts ----
        bf16x8 A[2][4];
        #pragma unroll
        for (int pt = 0; pt < 2; ++pt)
            #pragma unroll
            for (int s = 0; s < 4; ++s)
                A[pt][s] = *(const bf16x8*)&feaA[pt][l15][s * 32 + quad * 8];

        // ---- phase 2: 8 d-tiles, ONE wb set -> TWO independent MFMA chains ----
        #pragma unroll
        for (int n0 = 0; n0 < 8; ++n0) {
            const bf16x8 wb0 = *(const bf16x8*)(wbp + (n0 * 4 + 0) * 1024);
            const bf16x8 wb1 = *(const bf16x8*)(wbp + (n0 * 4 + 1) * 1024);
            const bf16x8 wb2 = *(const bf16x8*)(wbp + (n0 * 4 + 2) * 1024);
            const bf16x8 wb3 = *(const bf16x8*)(wbp + (n0 * 4 + 3) * 1024);
            f32x4 c0 = {0.f, 0.f, 0.f, 0.f};
            f32x4 c1 = {0.f, 0.f, 0.f, 0.f};
            __builtin_amdgcn_s_setprio(1);
            c0 = __builtin_amdgcn_mfma_f32_16x16x32_bf16(A[0][0], wb0, c0, 0, 0, 0);
            c1 = __builtin_amdgcn_mfma_f32_16x16x32_bf16(A[1][0], wb0, c1, 0, 0, 0);
            c0 = __builtin_amdgcn_mfma_f32_16x16x32_bf16(A[0][1], wb1, c0, 0, 0, 0);
            c1 = __builtin_amdgcn_mfma_f32_16x16x32_bf16(A[1][1], wb1, c1, 0, 0, 0);
            c0 = __builtin_amdgcn_mfma_f32_16x16x32_bf16(A[0][2], wb2, c0, 0, 0, 0);
            c1 = __builtin_amdgcn_mfma_f32_16x16x32_bf16(A[1][2], wb2, c1, 0, 0, 0);
            c0 = __builtin_amdgcn_mfma_f32_16x16x32_bf16(A[0][3], wb3, c0, 0, 0, 0);
            c1 = __builtin_amdgcn_mfma_f32_16x16x32_bf16(A[1][3], wb3, c1, 0, 0, 0);
            __builtin_amdgcn_s_setprio(0);

            // two independent softmax chains (VALU interleavable)
            const float e00 = __builtin_amdgcn_exp2f(c0[0]);
            const float e01 = __builtin_amdgcn_exp2f(c0[1]);
            const float e02 = __builtin_amdgcn_exp2f(c0[2]);
            const float e03 = __builtin_amdgcn_exp2f(c0[3]);
            const float e10 = __builtin_amdgcn_exp2f(c1[0]);
            const float e11 = __builtin_amdgcn_exp2f(c1[1]);
            const float e12 = __builtin_amdgcn_exp2f(c1[2]);
            const float e13 = __builtin_amdgcn_exp2f(c1[3]);
            float den0 = e00 + e01 + e02 + e03;
            float den1 = e10 + e11 + e12 + e13;
            float num0, num1;
            if (n0 < 4) {
                num0 = e00 * bf2f(feaA[0][quad * 4 + 0][n0 * 16 + l15])
                     + e01 * bf2f(feaA[0][quad * 4 + 1][n0 * 16 + l15])
                     + e02 * bf2f(feaA[0][quad * 4 + 2][n0 * 16 + l15])
                     + e03 * bf2f(feaA[0][quad * 4 + 3][n0 * 16 + l15]);
                num1 = e10 * bf2f(feaA[1][quad * 4 + 0][n0 * 16 + l15])
                     + e11 * bf2f(feaA[1][quad * 4 + 1][n0 * 16 + l15])
                     + e12 * bf2f(feaA[1][quad * 4 + 2][n0 * 16 + l15])
                     + e13 * bf2f(feaA[1][quad * 4 + 3][n0 * 16 + l15]);
            } else {
                num0 = e00 * nbC[0][n0 - 4][0] + e01 * nbC[0][n0 - 4][1]
                     + e02 * nbC[0][n0 - 4][2] + e03 * nbC[0][n0 - 4][3];
                num1 = e10 * nbC[1][n0 - 4][0] + e11 * nbC[1][n0 - 4][1]
                     + e12 * nbC[1][n0 - 4][2] + e13 * nbC[1][n0 - 4][3];
            }
            num0 += __shfl_xor(num0, 16, 64);
            den0 += __shfl_xor(den0, 16, 64);
            num1 += __shfl_xor(num1, 16, 64);
            den1 += __shfl_xor(den1, 16, 64);
            num0 += __shfl_xor(num0, 32, 64);
            den0 += __shfl_xor(den0, 32, 64);
            num1 += __shfl_xor(num1, 32, 64);
            den1 += __shfl_xor(den1, 32, 64);
            const float pp0v = __fdividef(num0, den0);
            const float pp1v = __fdividef(num1, den1);
            if (quad == 0) {
                pooledA[it * 2 + 0][n0 * 16 + l15] = f2bf(pp0v);
                pooledA[it * 2 + 1][n0 * 16 + l15] = f2bf(pp1v);
            }
        }
    }

    // ---- fused phase 3: out = lrelu([pooled|feat] @ W3hat + bias3), M=16 ----
    bf16x8 A3[6];
    #pragma unroll
    for (int s = 0; s < 6; ++s)
        A3[s] = *(const bf16x8*)&pooledA[l15][s * 32 + quad * 8];
    #pragma unroll
    for (int t = 0; t < 8; ++t) {
        f32x4 c = {0.f, 0.f, 0.f, 0.f};
        #pragma unroll
        for (int s = 0; s < 6; ++s) {
            const bf16x8 bw = *(const bf16x8*)(ws + WS_W3 + (((t * 6 + s) * 64 + lane) << 4));
            c = __builtin_amdgcn_mfma_f32_16x16x32_bf16(A3[s], bw, c, 0, 0, 0);
        }
        const float bz = ((const float*)(ws + WS_B3))[t * 16 + l15];
        #pragma unroll
        for (int r = 0; r < 4; ++r)
            out[(size_t)(p0 + quad * 4 + r) * COUT + t * 16 + l15] = lrelu(c[r] + bz);
    }
}

// ---------------------------------------------------------------------------
// Fallback main (exact r5 kernel, known 270 us): used if ws too small.
// ---------------------------------------------------------------------------
__global__ __launch_bounds__(256, 2) void lfa_main_f32(
    fp feature, fp raw, const int* __restrict__ nidx,
    const unsigned char* __restrict__ ws, float* __restrict__ out)
{
    __shared__ __align__(16) unsigned short feaA[4][16][136];
    __shared__ __align__(16) unsigned short pooledA[4][16][200];

    const int tid  = threadIdx.x;
    const int w    = tid >> 6;
    const int lane = tid & 63;
    const int quad = lane >> 4;
    const int l15  = lane & 15;
    const int p0   = (blockIdx.x * 4 + w) * 16;
    const int b    = p0 >> 16;

    bf16x8 WB[8][4];
    #pragma unroll
    for (int n0 = 0; n0 < 8; ++n0)
        #pragma unroll
        for (int s = 0; s < 4; ++s)
            WB[n0][s] = *(const bf16x8*)(ws + WS_WB + (((n0 * 4 + s) * 64 + lane) << 4));

    float binb[4];
    #pragma unroll
    for (int j = 0; j < 4; ++j)
        binb[j] = ((const float*)(ws + WS_BNB))[j * 16 + l15];

    #pragma unroll 1
    for (int it = 0; it < 8; ++it) {
        const int pp0 = p0 + it * 2;

        int idxv = 0;
        if (lane < 32) idxv = nidx[pp0 * KNB + lane];

        if (lane < 32) {
            const int pt = lane >> 4, c4 = l15 * 4;
            const float4 cf = *(const float4*)&feature[(size_t)(pp0 + pt) * CIN + c4];
            uint2 pk; pk.x = pack2(cf.x, cf.y); pk.y = pack2(cf.z, cf.w);
            *(uint2*)&pooledA[w][it * 2 + pt][CCAT + c4] = pk;
        }

        #pragma unroll
        for (int pt = 0; pt < 2; ++pt) {
            const int p = pp0 + pt;

            float4 gv[4];
            #pragma unroll
            for (int i = 0; i < 4; ++i) {
                const int ni = __shfl(idxv, pt * 16 + i * 4 + quad, 64);
                gv[i] = *(const float4*)&feature[(size_t)((b << 16) + ni) * CIN + l15 * 4];
            }

            bf16x8 anb = {0, 0, 0, 0, 0, 0, 0, 0};
            {
                const float* rp = raw + (size_t)p * (KNB * CR) + l15 * CR;
                if (quad == 0) {
                    const float2 r0 = *(const float2*)(rp + 0);
                    const float2 r1 = *(const float2*)(rp + 2);
                    const float2 r2 = *(const float2*)(rp + 4);
                    const float2 r3 = *(const float2*)(rp + 6);
                    anb[0] = (short)f2bf(r0.x); anb[1] = (short)f2bf(r0.y);
                    anb[2] = (short)f2bf(r1.x); anb[3] = (short)f2bf(r1.y);
                    anb[4] = (short)f2bf(r2.x); anb[5] = (short)f2bf(r2.y);
                    anb[6] = (short)f2bf(r3.x); anb[7] = (short)f2bf(r3.y);
                } else if (quad == 1) {
                    const float2 r4 = *(const float2*)(rp + 8);
                    anb[0] = (short)f2bf(r4.x); anb[1] = (short)f2bf(r4.y);
                }
            }

            float nbC[4][4];
            #pragma unroll
            for (int n0 = 0; n0 < 4; ++n0) {
                const bf16x8 bw = *(const bf16x8*)(ws + WS_WNB + ((n0 * 64 + lane) << 4));
                f32x4 c = {0.f, 0.f, 0.f, 0.f};
                c = __builtin_amdgcn_mfma_f32_16x16x32_bf16(anb, bw, c, 0, 0, 0);
                #pragma unroll
                for (int r = 0; r < 4; ++r) {
                    const float x = lrelu(c[r] + binb[n0]);
                    nbC[n0][r] = x;
                    feaA[w][quad * 4 + r][64 + n0 * 16 + l15] = f2bf(x);
                }
            }

            #pragma unroll
            for (int i = 0; i < 4; ++i) {
                uint2 pk; pk.x = pack2(gv[i].x, gv[i].y); pk.y = pack2(gv[i].z, gv[i].w);
                *(uint2*)&feaA[w][i * 4 + quad][l15 * 4] = pk;
            }

            bf16x8 A[4];
            #pragma unroll
            for (int s = 0; s < 4; ++s)
                A[s] = *(const bf16x8*)&feaA[w][l15][s * 32 + quad * 8];

            #pragma unroll
            for (int n0 = 0; n0 < 8; ++n0) {
                f32x4 c = {0.f, 0.f, 0.f, 0.f};
                #pragma unroll
                for (int s = 0; s < 4; ++s)
                    c = __builtin_amdgcn_mfma_f32_16x16x32_bf16(A[s], WB[n0][s], c, 0, 0, 0);
                const float e0 = __builtin_amdgcn_exp2f(c[0]);
                const float e1 = __builtin_amdgcn_exp2f(c[1]);
                const float e2 = __builtin_amdgcn_exp2f(c[2]);
                const float e3 = __builtin_amdgcn_exp2f(c[3]);
                float den = e0 + e1 + e2 + e3;
                float num;
                if (n0 < 4) {
                    num = e0 * bf2f(feaA[w][quad * 4 + 0][n0 * 16 + l15])
                        + e1 * bf2f(feaA[w][quad * 4 + 1][n0 * 16 + l15])
                        + e2 * bf2f(feaA[w][quad * 4 + 2][n0 * 16 + l15])
                        + e3 * bf2f(feaA[w][quad * 4 + 3][n0 * 16 + l15]);
                } else {
                    num = e0 * nbC[n0 - 4][0] + e1 * nbC[n0 - 4][1]
                        + e2 * nbC[n0 - 4][2] + e3 * nbC[n0 - 4][3];
                }
                num += __shfl_xor(num, 16, 64);
                den += __shfl_xor(den, 16, 64);
                num += __shfl_xor(num, 32, 64);
                den += __shfl_xor(den, 32, 64);
                const float pp = __fdividef(num, den);
                if (quad == 0)
                    pooledA[w][it * 2 + pt][n0 * 16 + l15] = f2bf(pp);
            }
        }
    }

    bf16x8 A3[6];
    #pragma unroll
    for (int s = 0; s < 6; ++s)
        A3[s] = *(const bf16x8*)&pooledA[w][l15][s * 32 + quad * 8];
    #pragma unroll
    for (int t = 0; t < 8; ++t) {
        f32x4 c = {0.f, 0.f, 0.f, 0.f};
        #pragma unroll
        for (int s = 0; s < 6; ++s) {
            const bf16x8 bw = *(const bf16x8*)(ws + WS_W3 + (((t * 6 + s) * 64 + lane) << 4));
            c = __builtin_amdgcn_mfma_f32_16x16x32_bf16(A3[s], bw, c, 0, 0, 0);
        }
        const float bz = ((const float*)(ws + WS_B3))[t * 16 + l15];
        #pragma unroll
        for (int r = 0; r < 4; ++r)
            out[(size_t)(p0 + quad * 4 + r) * COUT + t * 16 + l15] = lrelu(c[r] + bz);
    }
}

extern "C" void kernel_launch(void* const* d_in, const int* in_sizes, int n_in,
                              void* d_out, int out_size, void* d_ws, size_t ws_size,
                              hipStream_t stream)
{
    fp feature = (fp)d_in[1];
    fp raw     = (fp)d_in[2];
    const int* nidx = (const int*)d_in[3];
    fp W_nb = (fp)d_in[4],  b_nb = (fp)d_in[5],  g_nb = (fp)d_in[6];
    fp be_nb = (fp)d_in[7], m_nb = (fp)d_in[8],  v_nb = (fp)d_in[9];
    fp W_attn = (fp)d_in[10];
    fp W_out = (fp)d_in[11], b_out = (fp)d_in[12], g_out = (fp)d_in[13];
    fp be_out = (fp)d_in[14], m_out = (fp)d_in[15], v_out = (fp)d_in[16];
    fp W_sc = (fp)d_in[17], b_sc = (fp)d_in[18], g_sc = (fp)d_in[19];
    fp be_sc = (fp)d_in[20], m_sc = (fp)d_in[21], v_sc = (fp)d_in[22];

    hipLaunchKernelGGL(lfa_prep, dim3(22), dim3(256), 0, stream,
                       W_nb, b_nb, g_nb, be_nb, m_nb, v_nb,
                       W_attn,
                       W_out, b_out, g_out, be_out, m_out, v_out,
                       W_sc, b_sc, g_sc, be_sc, m_sc, v_sc,
                       (unsigned char*)d_ws);

    const size_t need = (size_t)WS_FEA + (size_t)NPTS * CIN * 2;
    if (ws_size >= need) {
        hipLaunchKernelGGL(lfa_prep_fea, dim3(4096), dim3(256), 0, stream,
                           feature, (unsigned char*)d_ws);
        hipLaunchKernelGGL(lfa_main_bf16, dim3(8192), dim3(64), 0, stream,
                           raw, nidx, (const unsigned char*)d_ws, (float*)d_out);
    } else {
        hipLaunchKernelGGL(lfa_main_f32, dim3(2048), dim3(256), 0, stream,
                           feature, raw, nidx,
                           (const unsigned char*)d_ws, (float*)d_out);
    }
}

// Round 13
// 364.058 us; speedup vs baseline: 1.3719x; 1.0920x over previous
//
#include <hip/hip_runtime.h>

// LocalFeatureAggregation — round 16: RESUBMIT of round 15 (infra failure,
// "MI355X container failed twice" — kernel never measured; no correctness or
// compile signal). Source identical to r15.
//
//  * r14 post-mortem: 233us, VGPR exactly 128, both changes confirmed.
//  * Remaining FIFO bug (r12's class): gathers issued BEFORE raw, but raw is
//    consumed FIRST (anb pack) -> FIFO vmcnt drains the ~600cy random gathers
//    to satisfy a ~300cy contiguous-raw wait. nb-MLP then runs with nothing
//    in flight.
//  * Fix: issue raw FIRST, gathers SECOND. Pack waits raw only (vmcnt leaves
//    8 gathers flying); nb-MLP (~350cy) covers the gather tail; gather-writes
//    wait ~0. Requires rw[2][4] live across gather issue (+16 regs).
//  * Paid for by deleting nbC[2][4][4] (-32 regs): softmax numerator reads nb
//    outputs back from feaA cols 64..127 (they're already written there),
//    unifying the n0<4 / n0>=4 branch into one path. bf16 rounding on those
//    terms matches what the n0<4 terms already do.
//  * Keep: int4 idx loads (no shfl), setprio on phase-2 MFMA cluster, hoisted
//    center rows, bf16 feature table, (64,2) bounds, VGPR<=128 law.
//  * Gates: VGPR <=128; WRITE ~65.5MB; FETCH ~147MB.
// Requires ws_size >= 16864256 for the fast path (>= 86784 for fallback).

#define KNB   16
#define CR    10
#define CIN   64
#define CCAT  128
#define COUT  128
#define NPTS  131072
#define EPS   1e-5f
#define LOG2E 1.4426950408889634f

// d_ws layout (bytes)
#define WS_WB   0        // W_attn B-frags (pre-scaled by log2e): 2048 * 16 B = 32768
#define WS_W3   32768    // [W_out;W_sc] BN-folded B-frags: 3072 * 16 B = 49152
#define WS_WNB  81920    // W_nb BN-folded B-frags (K padded to 32): 256 * 16 B = 4096
#define WS_B3   86016    // bias3[128] fp32
#define WS_BNB  86528    // binb[64] fp32   -> 86784
#define WS_FEA  87040    // bf16 feature table [NPTS][CIN]: 16777216 B -> total 16864256

typedef const float* fp;
typedef short bf16x8 __attribute__((ext_vector_type(8)));
typedef float f32x4  __attribute__((ext_vector_type(4)));
typedef __bf16 bf16x2 __attribute__((ext_vector_type(2)));

__device__ __forceinline__ unsigned short f2bf(float x) {
    return __builtin_bit_cast(unsigned short, (__bf16)x);     // HW RNE cvt
}
__device__ __forceinline__ unsigned int pack2(float a, float b) {
    bf16x2 v; v.x = (__bf16)a; v.y = (__bf16)b;               // v_cvt_pk_bf16_f32
    return __builtin_bit_cast(unsigned int, v);
}
__device__ __forceinline__ float bf2f(unsigned short h) {
    return __uint_as_float(((unsigned int)h) << 16);
}
__device__ __forceinline__ float lrelu(float x) { return fmaxf(x, 0.2f * x); }

// ---------------------------------------------------------------------------
// Prep: build all weight-fragment tables in d_ws.
// ---------------------------------------------------------------------------
__global__ __launch_bounds__(256) void lfa_prep(
    fp W_nb, fp b_nb, fp g_nb, fp be_nb, fp m_nb, fp v_nb,
    fp W_attn,
    fp W_out, fp b_out, fp g_out, fp be_out, fp m_out, fp v_out,
    fp W_sc,  fp b_sc,  fp g_sc,  fp be_sc,  fp m_sc,  fp v_sc,
    unsigned char* __restrict__ ws)
{
    const int t = blockIdx.x * 256 + threadIdx.x;
    if (t < 2048) {                                   // W_attn frags (x log2e)
        const int n0 = t >> 8, s = (t >> 6) & 3, ln = t & 63;
        const int n = (n0 << 4) + (ln & 15);
        unsigned int v[4];
        #pragma unroll
        for (int jj = 0; jj < 4; ++jj) {
            const int k = (s << 5) + ((ln >> 4) << 3) + jj * 2;
            v[jj] = pack2(W_attn[k * CCAT + n] * LOG2E,
                          W_attn[(k + 1) * CCAT + n] * LOG2E);
        }
        *(uint4*)(ws + WS_WB + t * 16) = make_uint4(v[0], v[1], v[2], v[3]);
    } else if (t < 5120) {                            // [W_out;W_sc] BN-folded frags
        const int e = t - 2048;
        const int t8 = e / 384, rem = e % 384, s = rem >> 6, ln = rem & 63;
        const int d = (t8 << 4) + (ln & 15);
        const float so = g_out[d] * rsqrtf(v_out[d] + EPS);
        const float ss = g_sc[d]  * rsqrtf(v_sc[d]  + EPS);
        unsigned int v[4];
        #pragma unroll
        for (int jj = 0; jj < 4; ++jj) {
            float a[2];
            #pragma unroll
            for (int h = 0; h < 2; ++h) {
                const int k = (s << 5) + ((ln >> 4) << 3) + jj * 2 + h;   // 0..191
                a[h] = (k < CCAT) ? W_out[k * COUT + d] * so
                                  : W_sc[(k - CCAT) * COUT + d] * ss;
            }
            v[jj] = pack2(a[0], a[1]);
        }
        *(uint4*)(ws + WS_W3 + e * 16) = make_uint4(v[0], v[1], v[2], v[3]);
    } else if (t < 5376) {                            // W_nb BN-prescaled frags
        const int e = t - 5120;
        const int n0 = e >> 6, ln = e & 63;
        const int n = (n0 << 4) + (ln & 15);
        const float sn = g_nb[n] * rsqrtf(v_nb[n] + EPS);
        unsigned int v[4];
        #pragma unroll
        for (int jj = 0; jj < 4; ++jj) {
            float a[2];
            #pragma unroll
            for (int h = 0; h < 2; ++h) {
                const int k = ((ln >> 4) << 3) + jj * 2 + h;
                a[h] = (k < CR) ? W_nb[k * 64 + n] * sn : 0.f;
            }
            v[jj] = pack2(a[0], a[1]);
        }
        *(uint4*)(ws + WS_WNB + e * 16) = make_uint4(v[0], v[1], v[2], v[3]);
    } else if (t < 5504) {                            // bias3
        const int d = t - 5376;
        const float so = g_out[d] * rsqrtf(v_out[d] + EPS);
        const float ss = g_sc[d]  * rsqrtf(v_sc[d]  + EPS);
        ((float*)(ws + WS_B3))[d] =
              (b_out[d] - m_out[d]) * so + be_out[d]
            + (b_sc[d]  - m_sc[d])  * ss + be_sc[d];
    } else if (t < 5568) {                            // nb bias
        const int d = t - 5504;
        const float sn = g_nb[d] * rsqrtf(v_nb[d] + EPS);
        ((float*)(ws + WS_BNB))[d] = (b_nb[d] - m_nb[d]) * sn + be_nb[d];
    }
}

// ---------------------------------------------------------------------------
// Prep 2: bf16 feature table [NPTS][CIN] into ws+WS_FEA (8 ch per thread).
// ---------------------------------------------------------------------------
__global__ __launch_bounds__(256) void lfa_prep_fea(
    fp feature, unsigned char* __restrict__ ws)
{
    const int t = blockIdx.x * 256 + threadIdx.x;
    const size_t idx = (size_t)t * 8;
    if (idx < (size_t)NPTS * CIN) {
        const float4 f0 = *(const float4*)&feature[idx];
        const float4 f1 = *(const float4*)&feature[idx + 4];
        uint4 o;
        o.x = pack2(f0.x, f0.y); o.y = pack2(f0.z, f0.w);
        o.z = pack2(f1.x, f1.y); o.w = pack2(f1.z, f1.w);
        *(uint4*)(ws + WS_FEA + idx * 2) = o;
    }
}

// ---------------------------------------------------------------------------
// Main (fast path): ONE WAVE PER BLOCK, point-paired inner loop, raw-first
// VMEM issue order, LDS-only nb outputs, setprio on MFMA cluster.
// 8192 blocks x 64 thr, 16 pts/block. LDS = 15104 B. VGPR target <=128.
// ---------------------------------------------------------------------------
__global__ __launch_bounds__(64, 2) void lfa_main_bf16(
    fp raw, const int* __restrict__ nidx,
    const unsigned char* __restrict__ ws, float* __restrict__ out)
{
    __shared__ __align__(16) unsigned short feaA[2][16][136];   // 8704 B
    __shared__ __align__(16) unsigned short pooledA[16][200];   // 6400 B

    const int lane = threadIdx.x;              // 0..63
    const int quad = lane >> 4;
    const int l15  = lane & 15;
    const int p0   = blockIdx.x * 16;          // block's 16 points
    const int b    = p0 >> 16;                 // batch (16-pt range never straddles)

    const unsigned short* feaT = (const unsigned short*)(ws + WS_FEA);
    const unsigned char*  wbp  = ws + WS_WB + ((size_t)lane << 4);

    // ---- hoisted: center rows for ALL 16 points -> pooledA[:,128..191] ----
    #pragma unroll
    for (int j = 0; j < 4; ++j) {
        const int e   = j * 64 + lane;         // 0..255
        const int row = e >> 4, c4 = (e & 15) * 4;
        const uint2 cf = *(const uint2*)&feaT[(size_t)(p0 + row) * CIN + c4];
        *(uint2*)&pooledA[row][CCAT + c4] = cf;
    }

    float binb[4];
    #pragma unroll
    for (int j = 0; j < 4; ++j)
        binb[j] = ((const float*)(ws + WS_BNB))[j * 16 + l15];

    #pragma unroll 1
    for (int it = 0; it < 8; ++it) {
        const int pp0 = p0 + it * 2;

        // ---- (a) neighbor indices, both pts (oldest VMEM; int4, no shfl) ----
        const int4 ni40 = *(const int4*)&nidx[(size_t)(pp0 + 0) * KNB + quad * 4];
        const int4 ni41 = *(const int4*)&nidx[(size_t)(pp0 + 1) * KNB + quad * 4];

        // ---- (b) raw loads issued BEFORE gathers (consumed first; FIFO) ----
        float2 rw[2][4];
        #pragma unroll
        for (int pt = 0; pt < 2; ++pt) {
            const float* rp = raw + (size_t)(pp0 + pt) * (KNB * CR) + l15 * CR;
            if (quad == 0) {
                rw[pt][0] = *(const float2*)(rp + 0);
                rw[pt][1] = *(const float2*)(rp + 2);
                rw[pt][2] = *(const float2*)(rp + 4);
                rw[pt][3] = *(const float2*)(rp + 6);
            } else if (quad == 1) {
                rw[pt][0] = *(const float2*)(rp + 8);
            }
        }

        // ---- (c) gathers (younger than raw; consumed after nb-MLP) ----
        uint2 gv[2][4];
        gv[0][0] = *(const uint2*)&feaT[(size_t)((b << 16) + ni40.x) * CIN + l15 * 4];
        gv[0][1] = *(const uint2*)&feaT[(size_t)((b << 16) + ni40.y) * CIN + l15 * 4];
        gv[0][2] = *(const uint2*)&feaT[(size_t)((b << 16) + ni40.z) * CIN + l15 * 4];
        gv[0][3] = *(const uint2*)&feaT[(size_t)((b << 16) + ni40.w) * CIN + l15 * 4];
        gv[1][0] = *(const uint2*)&feaT[(size_t)((b << 16) + ni41.x) * CIN + l15 * 4];
        gv[1][1] = *(const uint2*)&feaT[(size_t)((b << 16) + ni41.y) * CIN + l15 * 4];
        gv[1][2] = *(const uint2*)&feaT[(size_t)((b << 16) + ni41.z) * CIN + l15 * 4];
        gv[1][3] = *(const uint2*)&feaT[(size_t)((b << 16) + ni41.w) * CIN + l15 * 4];

        // ---- (d) anb pack — waits raw only (gathers keep flying) ----
        bf16x8 anb[2];
        #pragma unroll
        for (int pt = 0; pt < 2; ++pt) {
            bf16x8 a = {0, 0, 0, 0, 0, 0, 0, 0};
            if (quad == 0) {
                a[0] = (short)f2bf(rw[pt][0].x); a[1] = (short)f2bf(rw[pt][0].y);
                a[2] = (short)f2bf(rw[pt][1].x); a[3] = (short)f2bf(rw[pt][1].y);
                a[4] = (short)f2bf(rw[pt][2].x); a[5] = (short)f2bf(rw[pt][2].y);
                a[6] = (short)f2bf(rw[pt][3].x); a[7] = (short)f2bf(rw[pt][3].y);
            } else if (quad == 1) {
                a[0] = (short)f2bf(rw[pt][0].x); a[1] = (short)f2bf(rw[pt][0].y);
            }
            anb[pt] = a;
        }

        // ---- (e) nb-MLP: per-tile WNB frag -> two MFMAs -> feaA only ----
        #pragma unroll
        for (int n0 = 0; n0 < 4; ++n0) {
            const bf16x8 bw = *(const bf16x8*)(ws + WS_WNB + ((n0 * 64 + lane) << 4));
            f32x4 c0 = {0.f, 0.f, 0.f, 0.f};
            f32x4 c1 = {0.f, 0.f, 0.f, 0.f};
            c0 = __builtin_amdgcn_mfma_f32_16x16x32_bf16(anb[0], bw, c0, 0, 0, 0);
            c1 = __builtin_amdgcn_mfma_f32_16x16x32_bf16(anb[1], bw, c1, 0, 0, 0);
            #pragma unroll
            for (int r = 0; r < 4; ++r) {
                feaA[0][quad * 4 + r][64 + n0 * 16 + l15] = f2bf(lrelu(c0[r] + binb[n0]));
                feaA[1][quad * 4 + r][64 + n0 * 16 + l15] = f2bf(lrelu(c1[r] + binb[n0]));
            }
        }

        // ---- (f) gather writes (lane owns rows quad*4+i; wait ~0 by now) ----
        #pragma unroll
        for (int pt = 0; pt < 2; ++pt)
            #pragma unroll
            for (int i = 0; i < 4; ++i)
                *(uint2*)&feaA[pt][quad * 4 + i][l15 * 4] = gv[pt][i];

        // ---- attn A-frags for both pts ----
        bf16x8 A[2][4];
        #pragma unroll
        for (int pt = 0; pt < 2; ++pt)
            #pragma unroll
            for (int s = 0; s < 4; ++s)
                A[pt][s] = *(const bf16x8*)&feaA[pt][l15][s * 32 + quad * 8];

        // ---- phase 2: 8 d-tiles, ONE wb set -> TWO independent MFMA chains,
        //      unified softmax numerator (all n0 read feaA) ----
        #pragma unroll
        for (int n0 = 0; n0 < 8; ++n0) {
            const bf16x8 wb0 = *(const bf16x8*)(wbp + (n0 * 4 + 0) * 1024);
            const bf16x8 wb1 = *(const bf16x8*)(wbp + (n0 * 4 + 1) * 1024);
            const bf16x8 wb2 = *(const bf16x8*)(wbp + (n0 * 4 + 2) * 1024);
            const bf16x8 wb3 = *(const bf16x8*)(wbp + (n0 * 4 + 3) * 1024);
            f32x4 c0 = {0.f, 0.f, 0.f, 0.f};
            f32x4 c1 = {0.f, 0.f, 0.f, 0.f};
            __builtin_amdgcn_s_setprio(1);
            c0 = __builtin_amdgcn_mfma_f32_16x16x32_bf16(A[0][0], wb0, c0, 0, 0, 0);
            c1 = __builtin_amdgcn_mfma_f32_16x16x32_bf16(A[1][0], wb0, c1, 0, 0, 0);
            c0 = __builtin_amdgcn_mfma_f32_16x16x32_bf16(A[0][1], wb1, c0, 0, 0, 0);
            c1 = __builtin_amdgcn_mfma_f32_16x16x32_bf16(A[1][1], wb1, c1, 0, 0, 0);
            c0 = __builtin_amdgcn_mfma_f32_16x16x32_bf16(A[0][2], wb2, c0, 0, 0, 0);
            c1 = __builtin_amdgcn_mfma_f32_16x16x32_bf16(A[1][2], wb2, c1, 0, 0, 0);
            c0 = __builtin_amdgcn_mfma_f32_16x16x32_bf16(A[0][3], wb3, c0, 0, 0, 0);
            c1 = __builtin_amdgcn_mfma_f32_16x16x32_bf16(A[1][3], wb3, c1, 0, 0, 0);
            __builtin_amdgcn_s_setprio(0);

            const float e00 = __builtin_amdgcn_exp2f(c0[0]);
            const float e01 = __builtin_amdgcn_exp2f(c0[1]);
            const float e02 = __builtin_amdgcn_exp2f(c0[2]);
            const float e03 = __builtin_amdgcn_exp2f(c0[3]);
            const float e10 = __builtin_amdgcn_exp2f(c1[0]);
            const float e11 = __builtin_amdgcn_exp2f(c1[1]);
            const float e12 = __builtin_amdgcn_exp2f(c1[2]);
            const float e13 = __builtin_amdgcn_exp2f(c1[3]);
            float den0 = e00 + e01 + e02 + e03;
            float den1 = e10 + e11 + e12 + e13;
            float num0, num1;
            num0 = e00 * bf2f(feaA[0][quad * 4 + 0][n0 * 16 + l15])
                 + e01 * bf2f(feaA[0][quad * 4 + 1][n0 * 16 + l15])
                 + e02 * bf2f(feaA[0][quad * 4 + 2][n0 * 16 + l15])
                 + e03 * bf2f(feaA[0][quad * 4 + 3][n0 * 16 + l15]);
            num1 = e10 * bf2f(feaA[1][quad * 4 + 0][n0 * 16 + l15])
                 + e11 * bf2f(feaA[1][quad * 4 + 1][n0 * 16 + l15])
                 + e12 * bf2f(feaA[1][quad * 4 + 2][n0 * 16 + l15])
                 + e13 * bf2f(feaA[1][quad * 4 + 3][n0 * 16 + l15]);
            num0 += __shfl_xor(num0, 16, 64);
            den0 += __shfl_xor(den0, 16, 64);
            num1 += __shfl_xor(num1, 16, 64);
            den1 += __shfl_xor(den1, 16, 64);
            num0 += __shfl_xor(num0, 32, 64);
            den0 += __shfl_xor(den0, 32, 64);
            num1 += __shfl_xor(num1, 32, 64);
            den1 += __shfl_xor(den1, 32, 64);
            const float pp0v = __fdividef(num0, den0);
            const float pp1v = __fdividef(num1, den1);
            if (quad == 0) {
                pooledA[it * 2 + 0][n0 * 16 + l15] = f2bf(pp0v);
                pooledA[it * 2 + 1][n0 * 16 + l15] = f2bf(pp1v);
            }
        }
    }

    // ---- fused phase 3: out = lrelu([pooled|feat] @ W3hat + bias3), M=16 ----
    bf16x8 A3[6];
    #pragma unroll
    for (int s = 0; s < 6; ++s)
        A3[s] = *(const bf16x8*)&pooledA[l15][s * 32 + quad * 8];
    #pragma unroll
    for (int t = 0; t < 8; ++t) {
        f32x4 c = {0.f, 0.f, 0.f, 0.f};
        #pragma unroll
        for (int s = 0; s < 6; ++s) {
            const bf16x8 bw = *(const bf16x8*)(ws + WS_W3 + (((t * 6 + s) * 64 + lane) << 4));
            c = __builtin_amdgcn_mfma_f32_16x16x32_bf16(A3[s], bw, c, 0, 0, 0);
        }
        const float bz = ((const float*)(ws + WS_B3))[t * 16 + l15];
        #pragma unroll
        for (int r = 0; r < 4; ++r)
            out[(size_t)(p0 + quad * 4 + r) * COUT + t * 16 + l15] = lrelu(c[r] + bz);
    }
}

// ---------------------------------------------------------------------------
// Fallback main (exact r5 kernel, known 270 us): used if ws too small.
// ---------------------------------------------------------------------------
__global__ __launch_bounds__(256, 2) void lfa_main_f32(
    fp feature, fp raw, const int* __restrict__ nidx,
    const unsigned char* __restrict__ ws, float* __restrict__ out)
{
    __shared__ __align__(16) unsigned short feaA[4][16][136];
    __shared__ __align__(16) unsigned short pooledA[4][16][200];

    const int tid  = threadIdx.x;
    const int w    = tid >> 6;
    const int lane = tid & 63;
    const int quad = lane >> 4;
    const int l15  = lane & 15;
    const int p0   = (blockIdx.x * 4 + w) * 16;
    const int b    = p0 >> 16;

    bf16x8 WB[8][4];
    #pragma unroll
    for (int n0 = 0; n0 < 8; ++n0)
        #pragma unroll
        for (int s = 0; s < 4; ++s)
            WB[n0][s] = *(const bf16x8*)(ws + WS_WB + (((n0 * 4 + s) * 64 + lane) << 4));

    float binb[4];
    #pragma unroll
    for (int j = 0; j < 4; ++j)
        binb[j] = ((const float*)(ws + WS_BNB))[j * 16 + l15];

    #pragma unroll 1
    for (int it = 0; it < 8; ++it) {
        const int pp0 = p0 + it * 2;

        int idxv = 0;
        if (lane < 32) idxv = nidx[pp0 * KNB + lane];

        if (lane < 32) {
            const int pt = lane >> 4, c4 = l15 * 4;
            const float4 cf = *(const float4*)&feature[(size_t)(pp0 + pt) * CIN + c4];
            uint2 pk; pk.x = pack2(cf.x, cf.y); pk.y = pack2(cf.z, cf.w);
            *(uint2*)&pooledA[w][it * 2 + pt][CCAT + c4] = pk;
        }

        #pragma unroll
        for (int pt = 0; pt < 2; ++pt) {
            const int p = pp0 + pt;

            float4 gv[4];
            #pragma unroll
            for (int i = 0; i < 4; ++i) {
                const int ni = __shfl(idxv, pt * 16 + i * 4 + quad, 64);
                gv[i] = *(const float4*)&feature[(size_t)((b << 16) + ni) * CIN + l15 * 4];
            }

            bf16x8 anb = {0, 0, 0, 0, 0, 0, 0, 0};
            {
                const float* rp = raw + (size_t)p * (KNB * CR) + l15 * CR;
                if (quad == 0) {
                    const float2 r0 = *(const float2*)(rp + 0);
                    const float2 r1 = *(const float2*)(rp + 2);
                    const float2 r2 = *(const float2*)(rp + 4);
                    const float2 r3 = *(const float2*)(rp + 6);
                    anb[0] = (short)f2bf(r0.x); anb[1] = (short)f2bf(r0.y);
                    anb[2] = (short)f2bf(r1.x); anb[3] = (short)f2bf(r1.y);
                    anb[4] = (short)f2bf(r2.x); anb[5] = (short)f2bf(r2.y);
                    anb[6] = (short)f2bf(r3.x); anb[7] = (short)f2bf(r3.y);
                } else if (quad == 1) {
                    const float2 r4 = *(const float2*)(rp + 8);
                    anb[0] = (short)f2bf(r4.x); anb[1] = (short)f2bf(r4.y);
                }
            }

            float nbC[4][4];
            #pragma unroll
            for (int n0 = 0; n0 < 4; ++n0) {
                const bf16x8 bw = *(const bf16x8*)(ws + WS_WNB + ((n0 * 64 + lane) << 4));
                f32x4 c = {0.f, 0.f, 0.f, 0.f};
                c = __builtin_amdgcn_mfma_f32_16x16x32_bf16(anb, bw, c, 0, 0, 0);
                #pragma unroll
                for (int r = 0; r < 4; ++r) {
                    const float x = lrelu(c[r] + binb[n0]);
                    nbC[n0][r] = x;
                    feaA[w][quad * 4 + r][64 + n0 * 16 + l15] = f2bf(x);
                }
            }

            #pragma unroll
            for (int i = 0; i < 4; ++i) {
                uint2 pk; pk.x = pack2(gv[i].x, gv[i].y); pk.y = pack2(gv[i].z, gv[i].w);
                *(uint2*)&feaA[w][i * 4 + quad][l15 * 4] = pk;
            }

            bf16x8 A[4];
            #pragma unroll
            for (int s = 0; s < 4; ++s)
                A[s] = *(const bf16x8*)&feaA[w][l15][s * 32 + quad * 8];

            #pragma unroll
            for (int n0 = 0; n0 < 8; ++n0) {
                f32x4 c = {0.f, 0.f, 0.f, 0.f};
                #pragma unroll
                for (int s = 0; s < 4; ++s)
                    c = __builtin_amdgcn_mfma_f32_16x16x32_bf16(A[s], WB[n0][s], c, 0, 0, 0);
                const float e0 = __builtin_amdgcn_exp2f(c[0]);
                const float e1 = __builtin_amdgcn_exp2f(c[1]);
                const float e2 = __builtin_amdgcn_exp2f(c[2]);
                const float e3 = __builtin_amdgcn_exp2f(c[3]);
                float den = e0 + e1 + e2 + e3;
                float num;
                if (n0 < 4) {
                    num = e0 * bf2f(feaA[w][quad * 4 + 0][n0 * 16 + l15])
                        + e1 * bf2f(feaA[w][quad * 4 + 1][n0 * 16 + l15])
                        + e2 * bf2f(feaA[w][quad * 4 + 2][n0 * 16 + l15])
                        + e3 * bf2f(feaA[w][quad * 4 + 3][n0 * 16 + l15]);
                } else {
                    num = e0 * nbC[n0 - 4][0] + e1 * nbC[n0 - 4][1]
                        + e2 * nbC[n0 - 4][2] + e3 * nbC[n0 - 4][3];
                }
                num += __shfl_xor(num, 16, 64);
                den += __shfl_xor(den, 16, 64);
                num += __shfl_xor(num, 32, 64);
                den += __shfl_xor(den, 32, 64);
                const float pp = __fdividef(num, den);
                if (quad == 0)
                    pooledA[w][it * 2 + pt][n0 * 16 + l15] = f2bf(pp);
            }
        }
    }

    bf16x8 A3[6];
    #pragma unroll
    for (int s = 0; s < 6; ++s)
        A3[s] = *(const bf16x8*)&pooledA[w][l15][s * 32 + quad * 8];
    #pragma unroll
    for (int t = 0; t < 8; ++t) {
        f32x4 c = {0.f, 0.f, 0.f, 0.f};
        #pragma unroll
        for (int s = 0; s < 6; ++s) {
            const bf16x8 bw = *(const bf16x8*)(ws + WS_W3 + (((t * 6 + s) * 64 + lane) << 4));
            c = __builtin_amdgcn_mfma_f32_16x16x32_bf16(A3[s], bw, c, 0, 0, 0);
        }
        const float bz = ((const float*)(ws + WS_B3))[t * 16 + l15];
        #pragma unroll
        for (int r = 0; r < 4; ++r)
            out[(size_t)(p0 + quad * 4 + r) * COUT + t * 16 + l15] = lrelu(c[r] + bz);
    }
}

extern "C" void kernel_launch(void* const* d_in, const int* in_sizes, int n_in,
                              void* d_out, int out_size, void* d_ws, size_t ws_size,
                              hipStream_t stream)
{
    fp feature = (fp)d_in[1];
    fp raw     = (fp)d_in[2];
    const int* nidx = (const int*)d_in[3];
    fp W_nb = (fp)d_in[4],  b_nb = (fp)d_in[5],  g_nb = (fp)d_in[6];
    fp be_nb = (fp)d_in[7], m_nb = (fp)d_in[8],  v_nb = (fp)d_in[9];
    fp W_attn = (fp)d_in[10];
    fp W_out = (fp)d_in[11], b_out = (fp)d_in[12], g_out = (fp)d_in[13];
    fp be_out = (fp)d_in[14], m_out = (fp)d_in[15], v_out = (fp)d_in[16];
    fp W_sc = (fp)d_in[17], b_sc = (fp)d_in[18], g_sc = (fp)d_in[19];
    fp be_sc = (fp)d_in[20], m_sc = (fp)d_in[21], v_sc = (fp)d_in[22];

    hipLaunchKernelGGL(lfa_prep, dim3(22), dim3(256), 0, stream,
                       W_nb, b_nb, g_nb, be_nb, m_nb, v_nb,
                       W_attn,
                       W_out, b_out, g_out, be_out, m_out, v_out,
                       W_sc, b_sc, g_sc, be_sc, m_sc, v_sc,
                       (unsigned char*)d_ws);

    const size_t need = (size_t)WS_FEA + (size_t)NPTS * CIN * 2;
    if (ws_size >= need) {
        hipLaunchKernelGGL(lfa_prep_fea, dim3(4096), dim3(256), 0, stream,
                           feature, (unsigned char*)d_ws);
        hipLaunchKernelGGL(lfa_main_bf16, dim3(8192), dim3(64), 0, stream,
                           raw, nidx, (const unsigned char*)d_ws, (float*)d_out);
    } else {
        hipLaunchKernelGGL(lfa_main_f32, dim3(2048), dim3(256), 0, stream,
                           feature, raw, nidx,
                           (const unsigned char*)d_ws, (float*)d_out);
    }
}